// Round 12
// baseline (435.721 us; speedup 1.0000x reference)
//
#include <hip/hip_runtime.h>

typedef unsigned short u16;
typedef unsigned int u32;
typedef short s16x8 __attribute__((ext_vector_type(8)));
typedef u16 u16x4 __attribute__((ext_vector_type(4)));
typedef float f32x4 __attribute__((ext_vector_type(4)));
typedef u32 u32x2 __attribute__((ext_vector_type(2)));
typedef u32 u32x4 __attribute__((ext_vector_type(4)));

#define MFMA(a,b,c) __builtin_amdgcn_mfma_f32_16x16x32_bf16((a),(b),(c),0,0,0)

static const size_t PL = 16777216;  // elems per [65536][256] plane

__device__ __forceinline__ float b2f(u16 b) {
    return __uint_as_float(((unsigned int)b) << 16);
}
__device__ __forceinline__ u16 f2b(float f) {
    unsigned int u = __float_as_uint(f);
    unsigned int r = (u + 0x7FFFu + ((u >> 16) & 1u)) >> 16;
    return (u16)r;
}
__device__ __forceinline__ u32 cvtpk(float lo, float hi) {
    u32 r;
    asm("v_cvt_pk_bf16_f32 %0, %1, %2" : "=v"(r) : "v"(lo), "v"(hi));
    return r;
}
__device__ __forceinline__ float fexp2(float x) {
#if __has_builtin(__builtin_amdgcn_exp2f)
    return __builtin_amdgcn_exp2f(x);
#else
    return exp2f(x);
#endif
}

// load 8 bf16, apply interleaved-pair rotary in fp32, return bf16x8 (RTNE)
__device__ __forceinline__ s16x8 rot8(const u16* __restrict__ src,
                                      const float* __restrict__ cp,
                                      const float* __restrict__ sp) {
    s16x8 u = *(const s16x8*)src;
    f32x4 c0 = *(const f32x4*)cp, c1 = *(const f32x4*)(cp + 4);
    f32x4 s0 = *(const f32x4*)sp, s1 = *(const f32x4*)(sp + 4);
    float x[8];
#pragma unroll
    for (int j = 0; j < 8; j++) x[j] = b2f((u16)u[j]);
    float c[8] = {c0[0], c0[1], c0[2], c0[3], c1[0], c1[1], c1[2], c1[3]};
    float s[8] = {s0[0], s0[1], s0[2], s0[3], s1[0], s1[1], s1[2], s1[3]};
    u32x4 r;
#pragma unroll
    for (int p = 0; p < 4; p++) {
        float e = x[2 * p], o = x[2 * p + 1];
        float lo = e * c[2 * p] - o * s[2 * p];
        float hi = fmaf(e, s[2 * p + 1], o * c[2 * p + 1]);
        r[p] = cvtpk(lo, hi);
    }
    return __builtin_bit_cast(s16x8, r);
}

// ---------------- prep: x -> bf16 ----------------
__global__ void prep_x_k(const float* __restrict__ x, u16* __restrict__ xb) {
    size_t i = ((size_t)blockIdx.x * 256 + threadIdx.x) * 8;
    f32x4 a = *(const f32x4*)(x + i);
    f32x4 b = *(const f32x4*)(x + i + 4);
    u32x4 o = { cvtpk(a[0], a[1]), cvtpk(a[2], a[3]), cvtpk(b[0], b[1]), cvtpk(b[2], b[3]) };
    *(u32x4*)(xb + i) = o;
}

// ---------------- prep: W transposes (bf16) + rotary sincos tables ----------------
__global__ void prep_aux_k(const float* __restrict__ Wa, const float* __restrict__ Wp,
                           const float* __restrict__ rt, const float* __restrict__ rf,
                           u16* __restrict__ wt_a, u16* __restrict__ wt_p,
                           float* __restrict__ ct_t, float* __restrict__ st_t,
                           float* __restrict__ ct_f, float* __restrict__ st_f) {
    int i = blockIdx.x * 256 + threadIdx.x;
    if (i < 81920) {                       // W_attn^T: [1280][256]
        int idx = i * 4;
        int k = idx / 1280, n = idx - k * 1280;
        f32x4 v = *(const f32x4*)&Wa[idx];
#pragma unroll
        for (int j = 0; j < 4; j++) wt_a[(n + j) * 256 + k] = f2b(v[j]);
    } else if (i < 98304) {                // W_proj^T: [256][256]
        int idx = (i - 81920) * 4;
        int k = idx >> 8, n = idx & 255;
        f32x4 v = *(const f32x4*)&Wp[idx];
#pragma unroll
        for (int j = 0; j < 4; j++) wt_p[(n + j) * 256 + k] = f2b(v[j]);
    } else if (i < 100352) {               // rotary_t tables (256*32)
        int j = (i - 98304) * 4;
        f32x4 v = *(const f32x4*)&rt[j];
        f32x4 c, s;
#pragma unroll
        for (int jj = 0; jj < 4; jj++) { float ss, cc; __sincosf(v[jj], &ss, &cc); c[jj] = cc; s[jj] = ss; }
        *(f32x4*)&ct_t[j] = c; *(f32x4*)&st_t[j] = s;
    } else if (i < 100864) {               // rotary_f tables (64*32)
        int j = (i - 100352) * 4;
        f32x4 v = *(const f32x4*)&rf[j];
        f32x4 c, s;
#pragma unroll
        for (int jj = 0; jj < 4; jj++) { float ss, cc; __sincosf(v[jj], &ss, &cc); c[jj] = cc; s[jj] = ss; }
        *(f32x4*)&ct_f[j] = c; *(f32x4*)&st_f[j] = s;
    }
}

// ---------------- GEMM: C^T = Bt * A^T, A[M][256] bf16, Bt[N][256] bf16 ----------
// 1D grid, XCD-chunked swizzle (bijective): 512 M-tiles x NT N-tiles, N fastest.
// ALL global loads issued in prologue; BK=64 double-buffered LDS, unrolled.
// TO_PLANES: scatter bf16 into 5 attention-layout planes; else fp32 out[M][256]
template<int NT, bool TO_PLANES>
__global__ __launch_bounds__(256, 2) void gemm_k(const u16* __restrict__ A,
                                                 const u16* __restrict__ Bt,
                                                 u16* __restrict__ outp,
                                                 float* __restrict__ outf) {
    __shared__ __align__(16) u16 As[2][128][72];
    __shared__ __align__(16) u16 Bs[2][128][72];
    int bid = blockIdx.x;
    int xcd = bid & 7, slot = bid >> 3;
    int L = xcd * ((512 * NT) / 8) + slot;
    int mt = L / NT, nt = L - mt * NT;
    int m0 = mt * 128, n0 = nt * 128;
    int tid = threadIdx.x, lane = tid & 63, w = tid >> 6;
    int wm = w >> 1, wn = w & 1;
    int g = lane >> 4, lr = lane & 15;
    f32x4 acc[4][4] = {};   // acc[ni][mi] = C^T block
    s16x8 apb[4][4], bpb[4][4];   // [chunk][i] staging, all issued upfront

    auto loadAB = [&](int ch) {
#pragma unroll
        for (int i = 0; i < 4; i++) {
            int c = tid + i * 256, row = c >> 3, p = (c & 7) * 8;
            apb[ch][i] = *(const s16x8*)&A[(size_t)(m0 + row) * 256 + ch * 64 + p];
            bpb[ch][i] = *(const s16x8*)&Bt[(size_t)(n0 + row) * 256 + ch * 64 + p];
        }
    };
    auto storeAB = [&](int buf, int ch) {
#pragma unroll
        for (int i = 0; i < 4; i++) {
            int c = tid + i * 256, row = c >> 3, p = (c & 7) * 8;
            *(s16x8*)&As[buf][row][p] = apb[ch][i];
            *(s16x8*)&Bs[buf][row][p] = bpb[ch][i];
        }
    };

    // prologue: issue ALL loads; stage chunk 0
    loadAB(0); loadAB(1); loadAB(2); loadAB(3);
    storeAB(0, 0);
    __syncthreads();

#pragma unroll
    for (int s = 0; s < 4; s++) {
        int cur = s & 1;
        s16x8 af0[4], bf0[4];
#pragma unroll
        for (int mi = 0; mi < 4; mi++) af0[mi] = *(const s16x8*)&As[cur][wm * 64 + mi * 16 + lr][g * 8];
#pragma unroll
        for (int ni = 0; ni < 4; ni++) bf0[ni] = *(const s16x8*)&Bs[cur][wn * 64 + ni * 16 + lr][g * 8];
        if (s < 3) storeAB(cur ^ 1, s + 1);
#pragma unroll
        for (int ni = 0; ni < 4; ni++)
#pragma unroll
            for (int mi = 0; mi < 4; mi++)
                acc[ni][mi] = MFMA(bf0[ni], af0[mi], acc[ni][mi]);
        s16x8 af1[4], bf1[4];
#pragma unroll
        for (int mi = 0; mi < 4; mi++) af1[mi] = *(const s16x8*)&As[cur][wm * 64 + mi * 16 + lr][32 + g * 8];
#pragma unroll
        for (int ni = 0; ni < 4; ni++) bf1[ni] = *(const s16x8*)&Bs[cur][wn * 64 + ni * 16 + lr][32 + g * 8];
#pragma unroll
        for (int ni = 0; ni < 4; ni++)
#pragma unroll
            for (int mi = 0; mi < 4; mi++)
                acc[ni][mi] = MFMA(bf1[ni], af1[mi], acc[ni][mi]);
        __syncthreads();
    }

#pragma unroll
    for (int ni = 0; ni < 4; ni++) {
#pragma unroll
        for (int mi = 0; mi < 4; mi++) {
            int token = m0 + wm * 64 + mi * 16 + lr;
            int n = n0 + wn * 64 + ni * 16 + g * 4;
            if (TO_PLANES) {
                u32x2 pk = { cvtpk(acc[ni][mi][0], acc[ni][mi][1]),
                             cvtpk(acc[ni][mi][2], acc[ni][mi][3]) };
                int pl = n >> 8, c = n & 255, h = c >> 5, d0 = c & 31;
                int b = token >> 14, t = (token >> 6) & 255, f = token & 63;
                size_t addr = (pl == 1 || pl == 3)
                    ? ((size_t)(((b * 256 + t) * 8 + h) * 64 + f) * 32 + d0)
                    : ((size_t)(((b * 64 + f) * 8 + h) * 256 + t) * 32 + d0);
                *(u32x2*)&outp[(size_t)pl * PL + addr] = pk;
            } else {
                *(f32x4*)&outf[(size_t)token * 256 + n] = acc[ni][mi];
            }
        }
    }
}

// ---------------- time attention: one block per head (b,f,h); keys t=256 ----------
// K rotated DIRECTLY from global per fragment (coalesced 1KB spans, no LDS);
// V^T staged in LDS; barrier deferred behind qh=0's QK^T+softmax.
// layouts: q_t/k_t/v head-major idxT: head*8192 + t*32 + d ; y1 idxF
__global__ __launch_bounds__(256, 3) void attn_time_k(const u16* __restrict__ qt,
                                                      const u16* __restrict__ kt,
                                                      const u16* __restrict__ vp,
                                                      u16* __restrict__ y1,
                                                      const float* __restrict__ ct,
                                                      const float* __restrict__ st) {
    __shared__ __align__(16) u16 Vt[32][264];
    __shared__ __align__(16) u16 Pst[4][2][16][40];
    int bid = blockIdx.x;
    int xcd = bid & 7, slot = bid >> 3;
    int head = xcd * 256 + slot;                   // head = (b*64+f)*8+h, 2048 total
    int h = head & 7, f = (head >> 3) & 63, b = head >> 9;
    int tid = threadIdx.x, lane = tid & 63, w = tid >> 6;
    int g = lane >> 4, lr = lane & 15;
    const u16* Khead = kt + (size_t)head * 8192;
    const u16* Qhead = qt + (size_t)head * 8192;
    const u16* Vhead = vp + (size_t)head * 8192;

    // stage V^T
    {
        int ka = (tid & 63) * 4, db = (tid >> 6) * 8;
        const u16* vb = Vhead + (size_t)ka * 32 + db;
        s16x8 r0 = *(const s16x8*)(vb);
        s16x8 r1 = *(const s16x8*)(vb + 32);
        s16x8 r2 = *(const s16x8*)(vb + 64);
        s16x8 r3 = *(const s16x8*)(vb + 96);
#pragma unroll
        for (int dd = 0; dd < 8; dd++) {
            u16x4 pk = { (u16)r0[dd], (u16)r1[dd], (u16)r2[dd], (u16)r3[dd] };
            *(u16x4*)&Vt[db + dd][ka] = pk;
        }
    }

    const float sc2 = 0.17677669529663687f * 1.4426950408889634f;  // scale*log2e
    for (int qh = 0; qh < 2; qh++) {
        // Q fragments (rotated); wave owns q rows [qbase, qbase+32)
        int qbase = qh * 128 + w * 32;
        s16x8 qf_[2];
#pragma unroll
        for (int qi = 0; qi < 2; qi++) {
            int q = qbase + qi * 16 + lr;
            qf_[qi] = rot8(Qhead + q * 32 + g * 8, ct + q * 32 + g * 8, st + q * 32 + g * 8);
        }

        // S^T[key][q]: K fragment rotated from global (coalesced), no LDS
        f32x4 sT[16][2] = {};
#pragma unroll
        for (int ki = 0; ki < 16; ki++) {
            int key = ki * 16 + lr;
            s16x8 kf8 = rot8(Khead + key * 32 + g * 8, ct + key * 32 + g * 8, st + key * 32 + g * 8);
            sT[ki][0] = MFMA(kf8, qf_[0], sT[ki][0]);
            sT[ki][1] = MFMA(kf8, qf_[1], sT[ki][1]);
        }
        float rsum[2];
#pragma unroll
        for (int qi = 0; qi < 2; qi++) {
            float m = -1e30f;
#pragma unroll
            for (int ki = 0; ki < 16; ki++)
#pragma unroll
                for (int r = 0; r < 4; r++) m = fmaxf(m, sT[ki][qi][r]);
            m = fmaxf(m, __shfl_xor(m, 16));
            m = fmaxf(m, __shfl_xor(m, 32));
            float msc = m * sc2;
            float ssum = 0.f;
#pragma unroll
            for (int ki = 0; ki < 16; ki++)
#pragma unroll
                for (int r = 0; r < 4; r++) {
                    float p = fexp2(sT[ki][qi][r] * sc2 - msc);
                    sT[ki][qi][r] = p; ssum += p;
                }
            ssum += __shfl_xor(ssum, 16);
            ssum += __shfl_xor(ssum, 32);
            rsum[qi] = 1.0f / ssum;
        }

        if (qh == 0) __syncthreads();   // V^T ready; hidden behind QK^T+softmax

        // O^T[d][q] via per-wave streaming P^T redistribution (no barrier)
        f32x4 o_[2][2] = {};
#pragma unroll
        for (int ks = 0; ks < 8; ks++) {
            s16x8 vf0 = *(const s16x8*)&Vt[lr][ks * 32 + g * 8];
            s16x8 vf1 = *(const s16x8*)&Vt[16 + lr][ks * 32 + g * 8];
#pragma unroll
            for (int qi = 0; qi < 2; qi++) {
                u32x2 w0 = { cvtpk(sT[2 * ks][qi][0], sT[2 * ks][qi][1]),
                             cvtpk(sT[2 * ks][qi][2], sT[2 * ks][qi][3]) };
                u32x2 w1 = { cvtpk(sT[2 * ks + 1][qi][0], sT[2 * ks + 1][qi][1]),
                             cvtpk(sT[2 * ks + 1][qi][2], sT[2 * ks + 1][qi][3]) };
                *(u32x2*)&Pst[w][qi][lr][g * 4] = w0;
                *(u32x2*)&Pst[w][qi][lr][16 + g * 4] = w1;
                s16x8 pf = *(const s16x8*)&Pst[w][qi][lr][g * 8];
                o_[0][qi] = MFMA(vf0, pf, o_[0][qi]);
                o_[1][qi] = MFMA(vf1, pf, o_[1][qi]);
            }
        }
#pragma unroll
        for (int qi = 0; qi < 2; qi++) {
            int q = qbase + qi * 16 + lr;
            float rs = rsum[qi];
            u16* dst = y1 + ((size_t)(((b * 256 + q) * 8 + h) * 64 + f)) * 32;
#pragma unroll
            for (int di = 0; di < 2; di++) {
                u32x2 ob = { cvtpk(o_[di][qi][0] * rs, o_[di][qi][1] * rs),
                             cvtpk(o_[di][qi][2] * rs, o_[di][qi][3] * rs) };
                *(u32x2*)&dst[di * 16 + g * 4] = ob;
            }
        }
    }
}

// ---------------- frequency attention: wave per head (b,t,h); keys f=64 ----------
// K rotated directly from global per fragment; V^T per-wave LDS; no barriers.
// q_f/k_f/y1 idxF: head*2048 + f*32 + d ; y2 token-major
__global__ __launch_bounds__(256, 4) void attn_freq_k(const u16* __restrict__ qfp,
                                                      const u16* __restrict__ kfp,
                                                      const u16* __restrict__ y1,
                                                      u16* __restrict__ y2,
                                                      const float* __restrict__ ct,
                                                      const float* __restrict__ st) {
    __shared__ __align__(16) u16 Vt[4][32][72];
    __shared__ __align__(16) u16 Pst[4][2][16][40];
    int tid = threadIdx.x, lane = tid & 63, w = tid >> 6;
    int g = lane >> 4, lr = lane & 15;
    int head = blockIdx.x * 4 + w;                 // head = (b*256+t)*8+h
    int h = head & 7, t = (head >> 3) & 255, b = head >> 11;
    const u16* Khead = kfp + (size_t)head * 2048;
    const u16* Qhead = qfp + (size_t)head * 2048;
    const u16* Vhead = y1 + (size_t)head * 2048;

    // stage V^T (per-wave; same-wave DS ordering -> no barrier)
    {
        int ka = lr * 4, db = g * 8;
        const u16* vb = Vhead + (size_t)ka * 32 + db;
        s16x8 r0 = *(const s16x8*)(vb);
        s16x8 r1 = *(const s16x8*)(vb + 32);
        s16x8 r2 = *(const s16x8*)(vb + 64);
        s16x8 r3 = *(const s16x8*)(vb + 96);
#pragma unroll
        for (int dd = 0; dd < 8; dd++) {
            u16x4 pk = { (u16)r0[dd], (u16)r1[dd], (u16)r2[dd], (u16)r3[dd] };
            *(u16x4*)&Vt[w][db + dd][ka] = pk;
        }
    }
    s16x8 qfr[4];
#pragma unroll
    for (int qi = 0; qi < 4; qi++) {
        int q = qi * 16 + lr;
        qfr[qi] = rot8(Qhead + q * 32 + g * 8, ct + q * 32 + g * 8, st + q * 32 + g * 8);
    }

    f32x4 sT[4][4] = {};
#pragma unroll
    for (int ki = 0; ki < 4; ki++) {
        int key = ki * 16 + lr;
        s16x8 kf8 = rot8(Khead + key * 32 + g * 8, ct + key * 32 + g * 8, st + key * 32 + g * 8);
#pragma unroll
        for (int qi = 0; qi < 4; qi++) sT[ki][qi] = MFMA(kf8, qfr[qi], sT[ki][qi]);
    }
    const float sc2 = 0.17677669529663687f * 1.4426950408889634f;
    float rsum[4];
#pragma unroll
    for (int qi = 0; qi < 4; qi++) {
        float m = -1e30f;
#pragma unroll
        for (int ki = 0; ki < 4; ki++)
#pragma unroll
            for (int r = 0; r < 4; r++) m = fmaxf(m, sT[ki][qi][r]);
        m = fmaxf(m, __shfl_xor(m, 16));
        m = fmaxf(m, __shfl_xor(m, 32));
        float msc = m * sc2;
        float ssum = 0.f;
#pragma unroll
        for (int ki = 0; ki < 4; ki++)
#pragma unroll
            for (int r = 0; r < 4; r++) {
                float p = fexp2(sT[ki][qi][r] * sc2 - msc);
                sT[ki][qi][r] = p; ssum += p;
            }
        ssum += __shfl_xor(ssum, 16);
        ssum += __shfl_xor(ssum, 32);
        rsum[qi] = 1.0f / ssum;
    }

    f32x4 o_[2][4] = {};
#pragma unroll
    for (int ks = 0; ks < 2; ks++) {
        s16x8 vf0 = *(const s16x8*)&Vt[w][lr][ks * 32 + g * 8];
        s16x8 vf1 = *(const s16x8*)&Vt[w][16 + lr][ks * 32 + g * 8];
#pragma unroll
        for (int qi = 0; qi < 4; qi++) {
            u32x2 w0 = { cvtpk(sT[2 * ks][qi][0], sT[2 * ks][qi][1]),
                         cvtpk(sT[2 * ks][qi][2], sT[2 * ks][qi][3]) };
            u32x2 w1 = { cvtpk(sT[2 * ks + 1][qi][0], sT[2 * ks + 1][qi][1]),
                         cvtpk(sT[2 * ks + 1][qi][2], sT[2 * ks + 1][qi][3]) };
            *(u32x2*)&Pst[w][qi & 1][lr][g * 4] = w0;
            *(u32x2*)&Pst[w][qi & 1][lr][16 + g * 4] = w1;
            s16x8 pf = *(const s16x8*)&Pst[w][qi & 1][lr][g * 8];
            o_[0][qi] = MFMA(vf0, pf, o_[0][qi]);
            o_[1][qi] = MFMA(vf1, pf, o_[1][qi]);
        }
    }
#pragma unroll
    for (int qi = 0; qi < 4; qi++) {
        int q = qi * 16 + lr;
        float rs = rsum[qi];
        u16* dst = y2 + ((size_t)((b * 256 + t) * 64 + q)) * 256 + h * 32;
#pragma unroll
        for (int di = 0; di < 2; di++) {
            u32x2 ob = { cvtpk(o_[di][qi][0] * rs, o_[di][qi][1] * rs),
                         cvtpk(o_[di][qi][2] * rs, o_[di][qi][3] * rs) };
            *(u32x2*)&dst[di * 16 + g * 4] = ob;
        }
    }
}

// ---------------- launch ----------------
extern "C" void kernel_launch(void* const* d_in, const int* in_sizes, int n_in,
                              void* d_out, int out_size, void* d_ws, size_t ws_size,
                              hipStream_t stream) {
    const float* x  = (const float*)d_in[0];
    const float* Wa = (const float*)d_in[1];
    const float* Wp = (const float*)d_in[2];
    const float* rt = (const float*)d_in[3];
    const float* rf = (const float*)d_in[4];
    float* out = (float*)d_out;

    u16* planes = (u16*)d_ws;           // 5 planes: q_t,q_f,k_t,k_f,v
    u16* qt  = planes;                  // idxT
    u16* qfp = planes + PL;             // idxF
    u16* ktp = planes + 2 * PL;         // idxT
    u16* kfp = planes + 3 * PL;         // idxF
    u16* vp  = planes + 4 * PL;         // idxT
    u16* y1  = planes + 5 * PL;         // idxF (time-attn out)
    u16* xb  = y1;                      // bf16 x aliases y1 slot (dead before attn_time)
    u16* y2  = ktp;                     // token-major, aliases dead k_t
    float* ct_t = (float*)(planes + 6 * PL);
    float* st_t = ct_t + 8192;
    float* ct_f = st_t + 8192;
    float* st_f = ct_f + 2048;
    u16* wt_a = (u16*)(st_f + 2048);
    u16* wt_p = wt_a + 327680;

    prep_x_k<<<8192, 256, 0, stream>>>(x, xb);
    prep_aux_k<<<394, 256, 0, stream>>>(Wa, Wp, rt, rf, wt_a, wt_p, ct_t, st_t, ct_f, st_f);
    gemm_k<10, true><<<5120, 256, 0, stream>>>(xb, wt_a, planes, nullptr);
    attn_time_k<<<2048, 256, 0, stream>>>(qt, ktp, vp, y1, ct_t, st_t);
    attn_freq_k<<<2048, 256, 0, stream>>>(qfp, kfp, y1, y2, ct_f, st_f);
    gemm_k<2, false><<<1024, 256, 0, stream>>>(y2, wt_p, nullptr, out);
}

// Round 13
// 291.435 us; speedup vs baseline: 1.4951x; 1.4951x over previous
//
#include <hip/hip_runtime.h>

typedef unsigned short u16;
typedef unsigned int u32;
typedef short s16x8 __attribute__((ext_vector_type(8)));
typedef u16 u16x4 __attribute__((ext_vector_type(4)));
typedef float f32x4 __attribute__((ext_vector_type(4)));
typedef u32 u32x2 __attribute__((ext_vector_type(2)));
typedef u32 u32x4 __attribute__((ext_vector_type(4)));

#define MFMA(a,b,c) __builtin_amdgcn_mfma_f32_16x16x32_bf16((a),(b),(c),0,0,0)

static const size_t PL = 16777216;  // elems per [65536][256] plane

__device__ __forceinline__ float b2f(u16 b) {
    return __uint_as_float(((unsigned int)b) << 16);
}
__device__ __forceinline__ u16 f2b(float f) {
    unsigned int u = __float_as_uint(f);
    unsigned int r = (u + 0x7FFFu + ((u >> 16) & 1u)) >> 16;
    return (u16)r;
}
__device__ __forceinline__ u32 cvtpk(float lo, float hi) {
    u32 r;
    asm("v_cvt_pk_bf16_f32 %0, %1, %2" : "=v"(r) : "v"(lo), "v"(hi));
    return r;
}
__device__ __forceinline__ float fexp2(float x) {
#if __has_builtin(__builtin_amdgcn_exp2f)
    return __builtin_amdgcn_exp2f(x);
#else
    return exp2f(x);
#endif
}

// load 8 bf16, apply interleaved-pair rotary in fp32, return bf16x8 (RTNE)
__device__ __forceinline__ s16x8 rot8(const u16* __restrict__ src,
                                      const float* __restrict__ cp,
                                      const float* __restrict__ sp) {
    s16x8 u = *(const s16x8*)src;
    f32x4 c0 = *(const f32x4*)cp, c1 = *(const f32x4*)(cp + 4);
    f32x4 s0 = *(const f32x4*)sp, s1 = *(const f32x4*)(sp + 4);
    float x[8];
#pragma unroll
    for (int j = 0; j < 8; j++) x[j] = b2f((u16)u[j]);
    float c[8] = {c0[0], c0[1], c0[2], c0[3], c1[0], c1[1], c1[2], c1[3]};
    float s[8] = {s0[0], s0[1], s0[2], s0[3], s1[0], s1[1], s1[2], s1[3]};
    u32x4 r;
#pragma unroll
    for (int p = 0; p < 4; p++) {
        float e = x[2 * p], o = x[2 * p + 1];
        float lo = e * c[2 * p] - o * s[2 * p];
        float hi = fmaf(e, s[2 * p + 1], o * c[2 * p + 1]);
        r[p] = cvtpk(lo, hi);
    }
    return __builtin_bit_cast(s16x8, r);
}

// ---------------- prep: x -> bf16 ----------------
__global__ void prep_x_k(const float* __restrict__ x, u16* __restrict__ xb) {
    size_t i = ((size_t)blockIdx.x * 256 + threadIdx.x) * 8;
    f32x4 a = *(const f32x4*)(x + i);
    f32x4 b = *(const f32x4*)(x + i + 4);
    u32x4 o = { cvtpk(a[0], a[1]), cvtpk(a[2], a[3]), cvtpk(b[0], b[1]), cvtpk(b[2], b[3]) };
    *(u32x4*)(xb + i) = o;
}

// ---------------- prep: W transposes (bf16) + rotary sincos tables ----------------
__global__ void prep_aux_k(const float* __restrict__ Wa, const float* __restrict__ Wp,
                           const float* __restrict__ rt, const float* __restrict__ rf,
                           u16* __restrict__ wt_a, u16* __restrict__ wt_p,
                           float* __restrict__ ct_t, float* __restrict__ st_t,
                           float* __restrict__ ct_f, float* __restrict__ st_f) {
    int i = blockIdx.x * 256 + threadIdx.x;
    if (i < 81920) {                       // W_attn^T: [1280][256]
        int idx = i * 4;
        int k = idx / 1280, n = idx - k * 1280;
        f32x4 v = *(const f32x4*)&Wa[idx];
#pragma unroll
        for (int j = 0; j < 4; j++) wt_a[(n + j) * 256 + k] = f2b(v[j]);
    } else if (i < 98304) {                // W_proj^T: [256][256]
        int idx = (i - 81920) * 4;
        int k = idx >> 8, n = idx & 255;
        f32x4 v = *(const f32x4*)&Wp[idx];
#pragma unroll
        for (int j = 0; j < 4; j++) wt_p[(n + j) * 256 + k] = f2b(v[j]);
    } else if (i < 100352) {               // rotary_t tables (256*32)
        int j = (i - 98304) * 4;
        f32x4 v = *(const f32x4*)&rt[j];
        f32x4 c, s;
#pragma unroll
        for (int jj = 0; jj < 4; jj++) { float ss, cc; __sincosf(v[jj], &ss, &cc); c[jj] = cc; s[jj] = ss; }
        *(f32x4*)&ct_t[j] = c; *(f32x4*)&st_t[j] = s;
    } else if (i < 100864) {               // rotary_f tables (64*32)
        int j = (i - 100352) * 4;
        f32x4 v = *(const f32x4*)&rf[j];
        f32x4 c, s;
#pragma unroll
        for (int jj = 0; jj < 4; jj++) { float ss, cc; __sincosf(v[jj], &ss, &cc); c[jj] = cc; s[jj] = ss; }
        *(f32x4*)&ct_f[j] = c; *(f32x4*)&st_f[j] = s;
    }
}

// ---------------- GEMM: C^T = Bt * A^T, A[M][256] bf16, Bt[N][256] bf16 ----------
// 1D grid, XCD-chunked swizzle (bijective): 512 M-tiles x NT N-tiles, N fastest.
// ALL global loads issued in prologue; BK=64 double-buffered LDS, unrolled.
// TO_PLANES: scatter bf16 into 5 attention-layout planes; else fp32 out[M][256]
template<int NT, bool TO_PLANES>
__global__ __launch_bounds__(256, 2) void gemm_k(const u16* __restrict__ A,
                                                 const u16* __restrict__ Bt,
                                                 u16* __restrict__ outp,
                                                 float* __restrict__ outf) {
    __shared__ __align__(16) u16 As[2][128][72];
    __shared__ __align__(16) u16 Bs[2][128][72];
    int bid = blockIdx.x;
    int xcd = bid & 7, slot = bid >> 3;
    int L = xcd * ((512 * NT) / 8) + slot;
    int mt = L / NT, nt = L - mt * NT;
    int m0 = mt * 128, n0 = nt * 128;
    int tid = threadIdx.x, lane = tid & 63, w = tid >> 6;
    int wm = w >> 1, wn = w & 1;
    int g = lane >> 4, lr = lane & 15;
    f32x4 acc[4][4] = {};   // acc[ni][mi] = C^T block
    s16x8 apb[4][4], bpb[4][4];   // [chunk][i] staging, all issued upfront

    auto loadAB = [&](int ch) {
#pragma unroll
        for (int i = 0; i < 4; i++) {
            int c = tid + i * 256, row = c >> 3, p = (c & 7) * 8;
            apb[ch][i] = *(const s16x8*)&A[(size_t)(m0 + row) * 256 + ch * 64 + p];
            bpb[ch][i] = *(const s16x8*)&Bt[(size_t)(n0 + row) * 256 + ch * 64 + p];
        }
    };
    auto storeAB = [&](int buf, int ch) {
#pragma unroll
        for (int i = 0; i < 4; i++) {
            int c = tid + i * 256, row = c >> 3, p = (c & 7) * 8;
            *(s16x8*)&As[buf][row][p] = apb[ch][i];
            *(s16x8*)&Bs[buf][row][p] = bpb[ch][i];
        }
    };

    // prologue: issue ALL loads; stage chunk 0
    loadAB(0); loadAB(1); loadAB(2); loadAB(3);
    storeAB(0, 0);
    __syncthreads();

#pragma unroll
    for (int s = 0; s < 4; s++) {
        int cur = s & 1;
        s16x8 af0[4], bf0[4];
#pragma unroll
        for (int mi = 0; mi < 4; mi++) af0[mi] = *(const s16x8*)&As[cur][wm * 64 + mi * 16 + lr][g * 8];
#pragma unroll
        for (int ni = 0; ni < 4; ni++) bf0[ni] = *(const s16x8*)&Bs[cur][wn * 64 + ni * 16 + lr][g * 8];
        if (s < 3) storeAB(cur ^ 1, s + 1);
#pragma unroll
        for (int ni = 0; ni < 4; ni++)
#pragma unroll
            for (int mi = 0; mi < 4; mi++)
                acc[ni][mi] = MFMA(bf0[ni], af0[mi], acc[ni][mi]);
        s16x8 af1[4], bf1[4];
#pragma unroll
        for (int mi = 0; mi < 4; mi++) af1[mi] = *(const s16x8*)&As[cur][wm * 64 + mi * 16 + lr][32 + g * 8];
#pragma unroll
        for (int ni = 0; ni < 4; ni++) bf1[ni] = *(const s16x8*)&Bs[cur][wn * 64 + ni * 16 + lr][32 + g * 8];
#pragma unroll
        for (int ni = 0; ni < 4; ni++)
#pragma unroll
            for (int mi = 0; mi < 4; mi++)
                acc[ni][mi] = MFMA(bf1[ni], af1[mi], acc[ni][mi]);
        __syncthreads();
    }

#pragma unroll
    for (int ni = 0; ni < 4; ni++) {
#pragma unroll
        for (int mi = 0; mi < 4; mi++) {
            int token = m0 + wm * 64 + mi * 16 + lr;
            int n = n0 + wn * 64 + ni * 16 + g * 4;
            if (TO_PLANES) {
                u32x2 pk = { cvtpk(acc[ni][mi][0], acc[ni][mi][1]),
                             cvtpk(acc[ni][mi][2], acc[ni][mi][3]) };
                int pl = n >> 8, c = n & 255, h = c >> 5, d0 = c & 31;
                int b = token >> 14, t = (token >> 6) & 255, f = token & 63;
                size_t addr = (pl == 1 || pl == 3)
                    ? ((size_t)(((b * 256 + t) * 8 + h) * 64 + f) * 32 + d0)
                    : ((size_t)(((b * 64 + f) * 8 + h) * 256 + t) * 32 + d0);
                *(u32x2*)&outp[(size_t)pl * PL + addr] = pk;
            } else {
                *(f32x4*)&outf[(size_t)token * 256 + n] = acc[ni][mi];
            }
        }
    }
}

// ---------------- time attention: one block per head (b,f,h); keys t=256 ----------
// K/V staged+rotated ONCE in LDS (36/260 pads, single-buffer Pst -> 39.7KB,
// 4 blocks/CU), then both q-halves processed in-block.
// layouts: q_t/k_t/v head-major idxT: head*8192 + t*32 + d ; y1 idxF
__global__ __launch_bounds__(256, 4) void attn_time_k(const u16* __restrict__ qt,
                                                      const u16* __restrict__ kt,
                                                      const u16* __restrict__ vp,
                                                      u16* __restrict__ y1,
                                                      const float* __restrict__ ct,
                                                      const float* __restrict__ st) {
    __shared__ __align__(16) u16 K_l[256][36];
    __shared__ __align__(16) u16 Vt[32][260];
    __shared__ __align__(16) u16 Pst[4][16][36];
    int bid = blockIdx.x;
    int xcd = bid & 7, slot = bid >> 3;
    int head = xcd * 256 + slot;                   // head = (b*64+f)*8+h, 2048 total
    int h = head & 7, f = (head >> 3) & 63, b = head >> 9;
    int tid = threadIdx.x, lane = tid & 63, w = tid >> 6;
    int g = lane >> 4, lr = lane & 15;
    const u16* Khead = kt + (size_t)head * 8192;
    const u16* Qhead = qt + (size_t)head * 8192;
    const u16* Vhead = vp + (size_t)head * 8192;

    // stage K (rotated), coalesced: chunk c -> row c>>2, part c&3
#pragma unroll
    for (int i = 0; i < 4; i++) {
        int c = tid + i * 256;
        int t = c >> 2, p = (c & 3) * 8;
        *(s16x8*)&K_l[t][p] = rot8(Khead + t * 32 + p, ct + t * 32 + p, st + t * 32 + p);
    }
    // stage V^T
    {
        int ka = (tid & 63) * 4, db = (tid >> 6) * 8;
        const u16* vb = Vhead + (size_t)ka * 32 + db;
        s16x8 r0 = *(const s16x8*)(vb);
        s16x8 r1 = *(const s16x8*)(vb + 32);
        s16x8 r2 = *(const s16x8*)(vb + 64);
        s16x8 r3 = *(const s16x8*)(vb + 96);
#pragma unroll
        for (int dd = 0; dd < 8; dd++) {
            u16x4 pk = { (u16)r0[dd], (u16)r1[dd], (u16)r2[dd], (u16)r3[dd] };
            *(u16x4*)&Vt[db + dd][ka] = pk;
        }
    }
    __syncthreads();

    const float sc2 = 0.17677669529663687f * 1.4426950408889634f;  // scale*log2e
    for (int qh = 0; qh < 2; qh++) {
        // Q fragments (rotated); wave owns q rows [qbase, qbase+32)
        int qbase = qh * 128 + w * 32;
        s16x8 qf_[2];
#pragma unroll
        for (int qi = 0; qi < 2; qi++) {
            int q = qbase + qi * 16 + lr;
            qf_[qi] = rot8(Qhead + q * 32 + g * 8, ct + q * 32 + g * 8, st + q * 32 + g * 8);
        }

        // S^T[key][q]
        f32x4 sT[16][2] = {};
#pragma unroll
        for (int ki = 0; ki < 16; ki++) {
            s16x8 kf8 = *(const s16x8*)&K_l[ki * 16 + lr][g * 8];
            sT[ki][0] = MFMA(kf8, qf_[0], sT[ki][0]);
            sT[ki][1] = MFMA(kf8, qf_[1], sT[ki][1]);
        }
        float rsum[2];
#pragma unroll
        for (int qi = 0; qi < 2; qi++) {
            float m = -1e30f;
#pragma unroll
            for (int ki = 0; ki < 16; ki++)
#pragma unroll
                for (int r = 0; r < 4; r++) m = fmaxf(m, sT[ki][qi][r]);
            m = fmaxf(m, __shfl_xor(m, 16));
            m = fmaxf(m, __shfl_xor(m, 32));
            float msc = m * sc2;
            float ssum = 0.f;
#pragma unroll
            for (int ki = 0; ki < 16; ki++)
#pragma unroll
                for (int r = 0; r < 4; r++) {
                    float p = fexp2(sT[ki][qi][r] * sc2 - msc);
                    sT[ki][qi][r] = p; ssum += p;
                }
            ssum += __shfl_xor(ssum, 16);
            ssum += __shfl_xor(ssum, 32);
            rsum[qi] = 1.0f / ssum;
        }

        // O^T[d][q] via per-wave streaming P^T redistribution (single buffer:
        // same-wave DS ops are program-ordered -> sequential reuse is safe)
        f32x4 o_[2][2] = {};
#pragma unroll
        for (int ks = 0; ks < 8; ks++) {
            s16x8 vf0 = *(const s16x8*)&Vt[lr][ks * 32 + g * 8];
            s16x8 vf1 = *(const s16x8*)&Vt[16 + lr][ks * 32 + g * 8];
#pragma unroll
            for (int qi = 0; qi < 2; qi++) {
                u32x2 w0 = { cvtpk(sT[2 * ks][qi][0], sT[2 * ks][qi][1]),
                             cvtpk(sT[2 * ks][qi][2], sT[2 * ks][qi][3]) };
                u32x2 w1 = { cvtpk(sT[2 * ks + 1][qi][0], sT[2 * ks + 1][qi][1]),
                             cvtpk(sT[2 * ks + 1][qi][2], sT[2 * ks + 1][qi][3]) };
                *(u32x2*)&Pst[w][lr][g * 4] = w0;
                *(u32x2*)&Pst[w][lr][16 + g * 4] = w1;
                s16x8 pf = *(const s16x8*)&Pst[w][lr][g * 8];
                o_[0][qi] = MFMA(vf0, pf, o_[0][qi]);
                o_[1][qi] = MFMA(vf1, pf, o_[1][qi]);
            }
        }
#pragma unroll
        for (int qi = 0; qi < 2; qi++) {
            int q = qbase + qi * 16 + lr;
            float rs = rsum[qi];
            u16* dst = y1 + ((size_t)(((b * 256 + q) * 8 + h) * 64 + f)) * 32;
#pragma unroll
            for (int di = 0; di < 2; di++) {
                u32x2 ob = { cvtpk(o_[di][qi][0] * rs, o_[di][qi][1] * rs),
                             cvtpk(o_[di][qi][2] * rs, o_[di][qi][3] * rs) };
                *(u32x2*)&dst[di * 16 + g * 4] = ob;
            }
        }
    }
}

// ---------------- frequency attention: wave per head (b,t,h); keys f=64 ----------
// q_f/k_f/y1 idxF: head*2048 + f*32 + d ; y2 token-major ; 39.9KB LDS, 4 blocks/CU
__global__ __launch_bounds__(256, 4) void attn_freq_k(const u16* __restrict__ qfp,
                                                      const u16* __restrict__ kfp,
                                                      const u16* __restrict__ y1,
                                                      u16* __restrict__ y2,
                                                      const float* __restrict__ ct,
                                                      const float* __restrict__ st) {
    __shared__ __align__(16) u16 K_l[4][64][36];
    __shared__ __align__(16) u16 Vt[4][32][66];
    __shared__ __align__(16) u16 Pst[4][16][36];
    int tid = threadIdx.x, lane = tid & 63, w = tid >> 6;
    int g = lane >> 4, lr = lane & 15;
    int head = blockIdx.x * 4 + w;                 // head = (b*256+t)*8+h
    int h = head & 7, t = (head >> 3) & 255, b = head >> 11;
    const u16* Khead = kfp + (size_t)head * 2048;
    const u16* Qhead = qfp + (size_t)head * 2048;
    const u16* Vhead = y1 + (size_t)head * 2048;

    // stage K (rotated)
#pragma unroll
    for (int i = 0; i < 4; i++) {
        int c = i * 64 + lane;
        int row = c >> 2, p = (c & 3) * 8;
        *(s16x8*)&K_l[w][row][p] = rot8(Khead + row * 32 + p, ct + row * 32 + p, st + row * 32 + p);
    }
    // stage V^T (per-wave; same-wave DS ordering -> no barrier)
    {
        int ka = lr * 4, db = g * 8;
        const u16* vb = Vhead + (size_t)ka * 32 + db;
        s16x8 r0 = *(const s16x8*)(vb);
        s16x8 r1 = *(const s16x8*)(vb + 32);
        s16x8 r2 = *(const s16x8*)(vb + 64);
        s16x8 r3 = *(const s16x8*)(vb + 96);
#pragma unroll
        for (int dd = 0; dd < 8; dd++) {
            u16x4 pk = { (u16)r0[dd], (u16)r1[dd], (u16)r2[dd], (u16)r3[dd] };
            *(u16x4*)&Vt[w][db + dd][ka] = pk;
        }
    }
    s16x8 qfr[4];
#pragma unroll
    for (int qi = 0; qi < 4; qi++) {
        int q = qi * 16 + lr;
        qfr[qi] = rot8(Qhead + q * 32 + g * 8, ct + q * 32 + g * 8, st + q * 32 + g * 8);
    }
    // per-wave LDS only -> no __syncthreads needed

    f32x4 sT[4][4] = {};
#pragma unroll
    for (int ki = 0; ki < 4; ki++) {
        s16x8 kf8 = *(const s16x8*)&K_l[w][ki * 16 + lr][g * 8];
#pragma unroll
        for (int qi = 0; qi < 4; qi++) sT[ki][qi] = MFMA(kf8, qfr[qi], sT[ki][qi]);
    }
    const float sc2 = 0.17677669529663687f * 1.4426950408889634f;
    float rsum[4];
#pragma unroll
    for (int qi = 0; qi < 4; qi++) {
        float m = -1e30f;
#pragma unroll
        for (int ki = 0; ki < 4; ki++)
#pragma unroll
            for (int r = 0; r < 4; r++) m = fmaxf(m, sT[ki][qi][r]);
        m = fmaxf(m, __shfl_xor(m, 16));
        m = fmaxf(m, __shfl_xor(m, 32));
        float msc = m * sc2;
        float ssum = 0.f;
#pragma unroll
        for (int ki = 0; ki < 4; ki++)
#pragma unroll
            for (int r = 0; r < 4; r++) {
                float p = fexp2(sT[ki][qi][r] * sc2 - msc);
                sT[ki][qi][r] = p; ssum += p;
            }
        ssum += __shfl_xor(ssum, 16);
        ssum += __shfl_xor(ssum, 32);
        rsum[qi] = 1.0f / ssum;
    }

    f32x4 o_[2][4] = {};
#pragma unroll
    for (int ks = 0; ks < 2; ks++) {
        s16x8 vf0 = *(const s16x8*)&Vt[w][lr][ks * 32 + g * 8];
        s16x8 vf1 = *(const s16x8*)&Vt[w][16 + lr][ks * 32 + g * 8];
#pragma unroll
        for (int qi = 0; qi < 4; qi++) {
            u32x2 w0 = { cvtpk(sT[2 * ks][qi][0], sT[2 * ks][qi][1]),
                         cvtpk(sT[2 * ks][qi][2], sT[2 * ks][qi][3]) };
            u32x2 w1 = { cvtpk(sT[2 * ks + 1][qi][0], sT[2 * ks + 1][qi][1]),
                         cvtpk(sT[2 * ks + 1][qi][2], sT[2 * ks + 1][qi][3]) };
            *(u32x2*)&Pst[w][lr][g * 4] = w0;
            *(u32x2*)&Pst[w][lr][16 + g * 4] = w1;
            s16x8 pf = *(const s16x8*)&Pst[w][lr][g * 8];
            o_[0][qi] = MFMA(vf0, pf, o_[0][qi]);
            o_[1][qi] = MFMA(vf1, pf, o_[1][qi]);
        }
    }
#pragma unroll
    for (int qi = 0; qi < 4; qi++) {
        int q = qi * 16 + lr;
        float rs = rsum[qi];
        u16* dst = y2 + ((size_t)((b * 256 + t) * 64 + q)) * 256 + h * 32;
#pragma unroll
        for (int di = 0; di < 2; di++) {
            u32x2 ob = { cvtpk(o_[di][qi][0] * rs, o_[di][qi][1] * rs),
                         cvtpk(o_[di][qi][2] * rs, o_[di][qi][3] * rs) };
            *(u32x2*)&dst[di * 16 + g * 4] = ob;
        }
    }
}

// ---------------- launch ----------------
extern "C" void kernel_launch(void* const* d_in, const int* in_sizes, int n_in,
                              void* d_out, int out_size, void* d_ws, size_t ws_size,
                              hipStream_t stream) {
    const float* x  = (const float*)d_in[0];
    const float* Wa = (const float*)d_in[1];
    const float* Wp = (const float*)d_in[2];
    const float* rt = (const float*)d_in[3];
    const float* rf = (const float*)d_in[4];
    float* out = (float*)d_out;

    u16* planes = (u16*)d_ws;           // 5 planes: q_t,q_f,k_t,k_f,v
    u16* qt  = planes;                  // idxT
    u16* qfp = planes + PL;             // idxF
    u16* ktp = planes + 2 * PL;         // idxT
    u16* kfp = planes + 3 * PL;         // idxF
    u16* vp  = planes + 4 * PL;         // idxT
    u16* y1  = planes + 5 * PL;         // idxF (time-attn out)
    u16* xb  = y1;                      // bf16 x aliases y1 slot (dead before attn_time)
    u16* y2  = ktp;                     // token-major, aliases dead k_t
    float* ct_t = (float*)(planes + 6 * PL);
    float* st_t = ct_t + 8192;
    float* ct_f = st_t + 8192;
    float* st_f = ct_f + 2048;
    u16* wt_a = (u16*)(st_f + 2048);
    u16* wt_p = wt_a + 327680;

    prep_x_k<<<8192, 256, 0, stream>>>(x, xb);
    prep_aux_k<<<394, 256, 0, stream>>>(Wa, Wp, rt, rf, wt_a, wt_p, ct_t, st_t, ct_f, st_f);
    gemm_k<10, true><<<5120, 256, 0, stream>>>(xb, wt_a, planes, nullptr);
    attn_time_k<<<2048, 256, 0, stream>>>(qt, ktp, vp, y1, ct_t, st_t);
    attn_freq_k<<<2048, 256, 0, stream>>>(qfp, kfp, y1, y2, ct_f, st_f);
    gemm_k<2, false><<<1024, 256, 0, stream>>>(y2, wt_p, nullptr, out);
}

// Round 14
// 222.729 us; speedup vs baseline: 1.9563x; 1.3085x over previous
//
#include <hip/hip_runtime.h>

typedef unsigned short u16;
typedef unsigned int u32;
typedef short s16x8 __attribute__((ext_vector_type(8)));
typedef u16 u16x4 __attribute__((ext_vector_type(4)));
typedef float f32x4 __attribute__((ext_vector_type(4)));
typedef u32 u32x2 __attribute__((ext_vector_type(2)));
typedef u32 u32x4 __attribute__((ext_vector_type(4)));

#define MFMA(a,b,c) __builtin_amdgcn_mfma_f32_16x16x32_bf16((a),(b),(c),0,0,0)

static const size_t PL = 16777216;  // elems per [65536][256] plane

__device__ __forceinline__ float b2f(u16 b) {
    return __uint_as_float(((unsigned int)b) << 16);
}
__device__ __forceinline__ u16 f2b(float f) {
    unsigned int u = __float_as_uint(f);
    unsigned int r = (u + 0x7FFFu + ((u >> 16) & 1u)) >> 16;
    return (u16)r;
}
__device__ __forceinline__ u32 cvtpk(float lo, float hi) {
    u32 r;
    asm("v_cvt_pk_bf16_f32 %0, %1, %2" : "=v"(r) : "v"(lo), "v"(hi));
    return r;
}
__device__ __forceinline__ float fexp2(float x) {
#if __has_builtin(__builtin_amdgcn_exp2f)
    return __builtin_amdgcn_exp2f(x);
#else
    return exp2f(x);
#endif
}

// load 8 bf16, apply interleaved-pair rotary in fp32, return bf16x8 (RTNE)
__device__ __forceinline__ s16x8 rot8(const u16* __restrict__ src,
                                      const float* __restrict__ cp,
                                      const float* __restrict__ sp) {
    s16x8 u = *(const s16x8*)src;
    f32x4 c0 = *(const f32x4*)cp, c1 = *(const f32x4*)(cp + 4);
    f32x4 s0 = *(const f32x4*)sp, s1 = *(const f32x4*)(sp + 4);
    float x[8];
#pragma unroll
    for (int j = 0; j < 8; j++) x[j] = b2f((u16)u[j]);
    float c[8] = {c0[0], c0[1], c0[2], c0[3], c1[0], c1[1], c1[2], c1[3]};
    float s[8] = {s0[0], s0[1], s0[2], s0[3], s1[0], s1[1], s1[2], s1[3]};
    u32x4 r;
#pragma unroll
    for (int p = 0; p < 4; p++) {
        float e = x[2 * p], o = x[2 * p + 1];
        float lo = e * c[2 * p] - o * s[2 * p];
        float hi = fmaf(e, s[2 * p + 1], o * c[2 * p + 1]);
        r[p] = cvtpk(lo, hi);
    }
    return __builtin_bit_cast(s16x8, r);
}

// ---------------- prep: x -> bf16 ----------------
__global__ void prep_x_k(const float* __restrict__ x, u16* __restrict__ xb) {
    size_t i = ((size_t)blockIdx.x * 256 + threadIdx.x) * 8;
    f32x4 a = *(const f32x4*)(x + i);
    f32x4 b = *(const f32x4*)(x + i + 4);
    u32x4 o = { cvtpk(a[0], a[1]), cvtpk(a[2], a[3]), cvtpk(b[0], b[1]), cvtpk(b[2], b[3]) };
    *(u32x4*)(xb + i) = o;
}

// ---------------- prep: W transposes (bf16) + rotary sincos tables ----------------
__global__ void prep_aux_k(const float* __restrict__ Wa, const float* __restrict__ Wp,
                           const float* __restrict__ rt, const float* __restrict__ rf,
                           u16* __restrict__ wt_a, u16* __restrict__ wt_p,
                           float* __restrict__ ct_t, float* __restrict__ st_t,
                           float* __restrict__ ct_f, float* __restrict__ st_f) {
    int i = blockIdx.x * 256 + threadIdx.x;
    if (i < 81920) {                       // W_attn^T: [1280][256]
        int idx = i * 4;
        int k = idx / 1280, n = idx - k * 1280;
        f32x4 v = *(const f32x4*)&Wa[idx];
#pragma unroll
        for (int j = 0; j < 4; j++) wt_a[(n + j) * 256 + k] = f2b(v[j]);
    } else if (i < 98304) {                // W_proj^T: [256][256]
        int idx = (i - 81920) * 4;
        int k = idx >> 8, n = idx & 255;
        f32x4 v = *(const f32x4*)&Wp[idx];
#pragma unroll
        for (int j = 0; j < 4; j++) wt_p[(n + j) * 256 + k] = f2b(v[j]);
    } else if (i < 100352) {               // rotary_t tables (256*32)
        int j = (i - 98304) * 4;
        f32x4 v = *(const f32x4*)&rt[j];
        f32x4 c, s;
#pragma unroll
        for (int jj = 0; jj < 4; jj++) { float ss, cc; __sincosf(v[jj], &ss, &cc); c[jj] = cc; s[jj] = ss; }
        *(f32x4*)&ct_t[j] = c; *(f32x4*)&st_t[j] = s;
    } else if (i < 100864) {               // rotary_f tables (64*32)
        int j = (i - 100352) * 4;
        f32x4 v = *(const f32x4*)&rf[j];
        f32x4 c, s;
#pragma unroll
        for (int jj = 0; jj < 4; jj++) { float ss, cc; __sincosf(v[jj], &ss, &cc); c[jj] = cc; s[jj] = ss; }
        *(f32x4*)&ct_f[j] = c; *(f32x4*)&st_f[j] = s;
    }
}

// ---------------- GEMM: C^T = Bt * A^T, A[M][256] bf16, Bt[N][256] bf16 ----------
// 1D grid, XCD-chunked swizzle (bijective): 512 M-tiles x NT N-tiles, N fastest.
// ALL global loads issued in prologue; BK=64 double-buffered LDS, unrolled.
// TO_PLANES: scatter bf16 into 5 attention-layout planes; else fp32 out[M][256]
template<int NT, bool TO_PLANES>
__global__ __launch_bounds__(256, 2) void gemm_k(const u16* __restrict__ A,
                                                 const u16* __restrict__ Bt,
                                                 u16* __restrict__ outp,
                                                 float* __restrict__ outf) {
    __shared__ __align__(16) u16 As[2][128][72];
    __shared__ __align__(16) u16 Bs[2][128][72];
    int bid = blockIdx.x;
    int xcd = bid & 7, slot = bid >> 3;
    int L = xcd * ((512 * NT) / 8) + slot;
    int mt = L / NT, nt = L - mt * NT;
    int m0 = mt * 128, n0 = nt * 128;
    int tid = threadIdx.x, lane = tid & 63, w = tid >> 6;
    int wm = w >> 1, wn = w & 1;
    int g = lane >> 4, lr = lane & 15;
    f32x4 acc[4][4] = {};   // acc[ni][mi] = C^T block
    s16x8 apb[4][4], bpb[4][4];   // [chunk][i] staging, all issued upfront

    auto loadAB = [&](int ch) {
#pragma unroll
        for (int i = 0; i < 4; i++) {
            int c = tid + i * 256, row = c >> 3, p = (c & 7) * 8;
            apb[ch][i] = *(const s16x8*)&A[(size_t)(m0 + row) * 256 + ch * 64 + p];
            bpb[ch][i] = *(const s16x8*)&Bt[(size_t)(n0 + row) * 256 + ch * 64 + p];
        }
    };
    auto storeAB = [&](int buf, int ch) {
#pragma unroll
        for (int i = 0; i < 4; i++) {
            int c = tid + i * 256, row = c >> 3, p = (c & 7) * 8;
            *(s16x8*)&As[buf][row][p] = apb[ch][i];
            *(s16x8*)&Bs[buf][row][p] = bpb[ch][i];
        }
    };

    // prologue: issue ALL loads; stage chunk 0
    loadAB(0); loadAB(1); loadAB(2); loadAB(3);
    storeAB(0, 0);
    __syncthreads();

#pragma unroll
    for (int s = 0; s < 4; s++) {
        int cur = s & 1;
        s16x8 af0[4], bf0[4];
#pragma unroll
        for (int mi = 0; mi < 4; mi++) af0[mi] = *(const s16x8*)&As[cur][wm * 64 + mi * 16 + lr][g * 8];
#pragma unroll
        for (int ni = 0; ni < 4; ni++) bf0[ni] = *(const s16x8*)&Bs[cur][wn * 64 + ni * 16 + lr][g * 8];
        if (s < 3) storeAB(cur ^ 1, s + 1);
#pragma unroll
        for (int ni = 0; ni < 4; ni++)
#pragma unroll
            for (int mi = 0; mi < 4; mi++)
                acc[ni][mi] = MFMA(bf0[ni], af0[mi], acc[ni][mi]);
        s16x8 af1[4], bf1[4];
#pragma unroll
        for (int mi = 0; mi < 4; mi++) af1[mi] = *(const s16x8*)&As[cur][wm * 64 + mi * 16 + lr][32 + g * 8];
#pragma unroll
        for (int ni = 0; ni < 4; ni++) bf1[ni] = *(const s16x8*)&Bs[cur][wn * 64 + ni * 16 + lr][32 + g * 8];
#pragma unroll
        for (int ni = 0; ni < 4; ni++)
#pragma unroll
            for (int mi = 0; mi < 4; mi++)
                acc[ni][mi] = MFMA(bf1[ni], af1[mi], acc[ni][mi]);
        __syncthreads();
    }

#pragma unroll
    for (int ni = 0; ni < 4; ni++) {
#pragma unroll
        for (int mi = 0; mi < 4; mi++) {
            int token = m0 + wm * 64 + mi * 16 + lr;
            int n = n0 + wn * 64 + ni * 16 + g * 4;
            if (TO_PLANES) {
                u32x2 pk = { cvtpk(acc[ni][mi][0], acc[ni][mi][1]),
                             cvtpk(acc[ni][mi][2], acc[ni][mi][3]) };
                int pl = n >> 8, c = n & 255, h = c >> 5, d0 = c & 31;
                int b = token >> 14, t = (token >> 6) & 255, f = token & 63;
                size_t addr = (pl == 1 || pl == 3)
                    ? ((size_t)(((b * 256 + t) * 8 + h) * 64 + f) * 32 + d0)
                    : ((size_t)(((b * 64 + f) * 8 + h) * 256 + t) * 32 + d0);
                *(u32x2*)&outp[(size_t)pl * PL + addr] = pk;
            } else {
                *(f32x4*)&outf[(size_t)token * 256 + n] = acc[ni][mi];
            }
        }
    }
}

// ---------------- time attention: one block per head (b,f,h); keys t=256 ----------
// K/V staged+rotated ONCE in LDS (36/260 pads, single-buffer Pst -> 39.7KB).
// launch_bounds(256,3): VGPR cap 170 (no spill, alloc ~84) -> HW reaches 4 blocks/CU
// via the LDS fit; bounds(256,4) would cap VGPR at 128 and spill (round-13 lesson).
// layouts: q_t/k_t/v head-major idxT: head*8192 + t*32 + d ; y1 idxF
__global__ __launch_bounds__(256, 3) void attn_time_k(const u16* __restrict__ qt,
                                                      const u16* __restrict__ kt,
                                                      const u16* __restrict__ vp,
                                                      u16* __restrict__ y1,
                                                      const float* __restrict__ ct,
                                                      const float* __restrict__ st) {
    __shared__ __align__(16) u16 K_l[256][36];
    __shared__ __align__(16) u16 Vt[32][260];
    __shared__ __align__(16) u16 Pst[4][16][36];
    int bid = blockIdx.x;
    int xcd = bid & 7, slot = bid >> 3;
    int head = xcd * 256 + slot;                   // head = (b*64+f)*8+h, 2048 total
    int h = head & 7, f = (head >> 3) & 63, b = head >> 9;
    int tid = threadIdx.x, lane = tid & 63, w = tid >> 6;
    int g = lane >> 4, lr = lane & 15;
    const u16* Khead = kt + (size_t)head * 8192;
    const u16* Qhead = qt + (size_t)head * 8192;
    const u16* Vhead = vp + (size_t)head * 8192;

    // stage K (rotated), coalesced: chunk c -> row c>>2, part c&3
#pragma unroll
    for (int i = 0; i < 4; i++) {
        int c = tid + i * 256;
        int t = c >> 2, p = (c & 3) * 8;
        *(s16x8*)&K_l[t][p] = rot8(Khead + t * 32 + p, ct + t * 32 + p, st + t * 32 + p);
    }
    // stage V^T
    {
        int ka = (tid & 63) * 4, db = (tid >> 6) * 8;
        const u16* vb = Vhead + (size_t)ka * 32 + db;
        s16x8 r0 = *(const s16x8*)(vb);
        s16x8 r1 = *(const s16x8*)(vb + 32);
        s16x8 r2 = *(const s16x8*)(vb + 64);
        s16x8 r3 = *(const s16x8*)(vb + 96);
#pragma unroll
        for (int dd = 0; dd < 8; dd++) {
            u16x4 pk = { (u16)r0[dd], (u16)r1[dd], (u16)r2[dd], (u16)r3[dd] };
            *(u16x4*)&Vt[db + dd][ka] = pk;
        }
    }
    __syncthreads();

    const float sc2 = 0.17677669529663687f * 1.4426950408889634f;  // scale*log2e
    for (int qh = 0; qh < 2; qh++) {
        // Q fragments (rotated); wave owns q rows [qbase, qbase+32)
        int qbase = qh * 128 + w * 32;
        s16x8 qf_[2];
#pragma unroll
        for (int qi = 0; qi < 2; qi++) {
            int q = qbase + qi * 16 + lr;
            qf_[qi] = rot8(Qhead + q * 32 + g * 8, ct + q * 32 + g * 8, st + q * 32 + g * 8);
        }

        // S^T[key][q]
        f32x4 sT[16][2] = {};
#pragma unroll
        for (int ki = 0; ki < 16; ki++) {
            s16x8 kf8 = *(const s16x8*)&K_l[ki * 16 + lr][g * 8];
            sT[ki][0] = MFMA(kf8, qf_[0], sT[ki][0]);
            sT[ki][1] = MFMA(kf8, qf_[1], sT[ki][1]);
        }
        float rsum[2];
#pragma unroll
        for (int qi = 0; qi < 2; qi++) {
            float m = -1e30f;
#pragma unroll
            for (int ki = 0; ki < 16; ki++)
#pragma unroll
                for (int r = 0; r < 4; r++) m = fmaxf(m, sT[ki][qi][r]);
            m = fmaxf(m, __shfl_xor(m, 16));
            m = fmaxf(m, __shfl_xor(m, 32));
            float msc = m * sc2;
            float ssum = 0.f;
#pragma unroll
            for (int ki = 0; ki < 16; ki++)
#pragma unroll
                for (int r = 0; r < 4; r++) {
                    float p = fexp2(sT[ki][qi][r] * sc2 - msc);
                    sT[ki][qi][r] = p; ssum += p;
                }
            ssum += __shfl_xor(ssum, 16);
            ssum += __shfl_xor(ssum, 32);
            rsum[qi] = 1.0f / ssum;
        }

        // O^T[d][q] via per-wave streaming P^T redistribution (single buffer:
        // same-wave DS ops are program-ordered -> sequential reuse is safe)
        f32x4 o_[2][2] = {};
#pragma unroll
        for (int ks = 0; ks < 8; ks++) {
            s16x8 vf0 = *(const s16x8*)&Vt[lr][ks * 32 + g * 8];
            s16x8 vf1 = *(const s16x8*)&Vt[16 + lr][ks * 32 + g * 8];
#pragma unroll
            for (int qi = 0; qi < 2; qi++) {
                u32x2 w0 = { cvtpk(sT[2 * ks][qi][0], sT[2 * ks][qi][1]),
                             cvtpk(sT[2 * ks][qi][2], sT[2 * ks][qi][3]) };
                u32x2 w1 = { cvtpk(sT[2 * ks + 1][qi][0], sT[2 * ks + 1][qi][1]),
                             cvtpk(sT[2 * ks + 1][qi][2], sT[2 * ks + 1][qi][3]) };
                *(u32x2*)&Pst[w][lr][g * 4] = w0;
                *(u32x2*)&Pst[w][lr][16 + g * 4] = w1;
                s16x8 pf = *(const s16x8*)&Pst[w][lr][g * 8];
                o_[0][qi] = MFMA(vf0, pf, o_[0][qi]);
                o_[1][qi] = MFMA(vf1, pf, o_[1][qi]);
            }
        }
#pragma unroll
        for (int qi = 0; qi < 2; qi++) {
            int q = qbase + qi * 16 + lr;
            float rs = rsum[qi];
            u16* dst = y1 + ((size_t)(((b * 256 + q) * 8 + h) * 64 + f)) * 32;
#pragma unroll
            for (int di = 0; di < 2; di++) {
                u32x2 ob = { cvtpk(o_[di][qi][0] * rs, o_[di][qi][1] * rs),
                             cvtpk(o_[di][qi][2] * rs, o_[di][qi][3] * rs) };
                *(u32x2*)&dst[di * 16 + g * 4] = ob;
            }
        }
    }
}

// ---------------- frequency attention: wave per head (b,t,h); keys f=64 ----------
// q_f/k_f/y1 idxF: head*2048 + f*32 + d ; y2 token-major ; 39.9KB LDS,
// launch_bounds(256,3) -> no VGPR spill, HW can reach 4 blocks/CU via LDS fit.
__global__ __launch_bounds__(256, 3) void attn_freq_k(const u16* __restrict__ qfp,
                                                      const u16* __restrict__ kfp,
                                                      const u16* __restrict__ y1,
                                                      u16* __restrict__ y2,
                                                      const float* __restrict__ ct,
                                                      const float* __restrict__ st) {
    __shared__ __align__(16) u16 K_l[4][64][36];
    __shared__ __align__(16) u16 Vt[4][32][66];
    __shared__ __align__(16) u16 Pst[4][16][36];
    int tid = threadIdx.x, lane = tid & 63, w = tid >> 6;
    int g = lane >> 4, lr = lane & 15;
    int head = blockIdx.x * 4 + w;                 // head = (b*256+t)*8+h
    int h = head & 7, t = (head >> 3) & 255, b = head >> 11;
    const u16* Khead = kfp + (size_t)head * 2048;
    const u16* Qhead = qfp + (size_t)head * 2048;
    const u16* Vhead = y1 + (size_t)head * 2048;

    // stage K (rotated)
#pragma unroll
    for (int i = 0; i < 4; i++) {
        int c = i * 64 + lane;
        int row = c >> 2, p = (c & 3) * 8;
        *(s16x8*)&K_l[w][row][p] = rot8(Khead + row * 32 + p, ct + row * 32 + p, st + row * 32 + p);
    }
    // stage V^T (per-wave; same-wave DS ordering -> no barrier)
    {
        int ka = lr * 4, db = g * 8;
        const u16* vb = Vhead + (size_t)ka * 32 + db;
        s16x8 r0 = *(const s16x8*)(vb);
        s16x8 r1 = *(const s16x8*)(vb + 32);
        s16x8 r2 = *(const s16x8*)(vb + 64);
        s16x8 r3 = *(const s16x8*)(vb + 96);
#pragma unroll
        for (int dd = 0; dd < 8; dd++) {
            u16x4 pk = { (u16)r0[dd], (u16)r1[dd], (u16)r2[dd], (u16)r3[dd] };
            *(u16x4*)&Vt[w][db + dd][ka] = pk;
        }
    }
    s16x8 qfr[4];
#pragma unroll
    for (int qi = 0; qi < 4; qi++) {
        int q = qi * 16 + lr;
        qfr[qi] = rot8(Qhead + q * 32 + g * 8, ct + q * 32 + g * 8, st + q * 32 + g * 8);
    }
    // per-wave LDS only -> no __syncthreads needed

    f32x4 sT[4][4] = {};
#pragma unroll
    for (int ki = 0; ki < 4; ki++) {
        s16x8 kf8 = *(const s16x8*)&K_l[w][ki * 16 + lr][g * 8];
#pragma unroll
        for (int qi = 0; qi < 4; qi++) sT[ki][qi] = MFMA(kf8, qfr[qi], sT[ki][qi]);
    }
    const float sc2 = 0.17677669529663687f * 1.4426950408889634f;
    float rsum[4];
#pragma unroll
    for (int qi = 0; qi < 4; qi++) {
        float m = -1e30f;
#pragma unroll
        for (int ki = 0; ki < 4; ki++)
#pragma unroll
            for (int r = 0; r < 4; r++) m = fmaxf(m, sT[ki][qi][r]);
        m = fmaxf(m, __shfl_xor(m, 16));
        m = fmaxf(m, __shfl_xor(m, 32));
        float msc = m * sc2;
        float ssum = 0.f;
#pragma unroll
        for (int ki = 0; ki < 4; ki++)
#pragma unroll
            for (int r = 0; r < 4; r++) {
                float p = fexp2(sT[ki][qi][r] * sc2 - msc);
                sT[ki][qi][r] = p; ssum += p;
            }
        ssum += __shfl_xor(ssum, 16);
        ssum += __shfl_xor(ssum, 32);
        rsum[qi] = 1.0f / ssum;
    }

    f32x4 o_[2][4] = {};
#pragma unroll
    for (int ks = 0; ks < 2; ks++) {
        s16x8 vf0 = *(const s16x8*)&Vt[w][lr][ks * 32 + g * 8];
        s16x8 vf1 = *(const s16x8*)&Vt[w][16 + lr][ks * 32 + g * 8];
#pragma unroll
        for (int qi = 0; qi < 4; qi++) {
            u32x2 w0 = { cvtpk(sT[2 * ks][qi][0], sT[2 * ks][qi][1]),
                         cvtpk(sT[2 * ks][qi][2], sT[2 * ks][qi][3]) };
            u32x2 w1 = { cvtpk(sT[2 * ks + 1][qi][0], sT[2 * ks + 1][qi][1]),
                         cvtpk(sT[2 * ks + 1][qi][2], sT[2 * ks + 1][qi][3]) };
            *(u32x2*)&Pst[w][lr][g * 4] = w0;
            *(u32x2*)&Pst[w][lr][16 + g * 4] = w1;
            s16x8 pf = *(const s16x8*)&Pst[w][lr][g * 8];
            o_[0][qi] = MFMA(vf0, pf, o_[0][qi]);
            o_[1][qi] = MFMA(vf1, pf, o_[1][qi]);
        }
    }
#pragma unroll
    for (int qi = 0; qi < 4; qi++) {
        int q = qi * 16 + lr;
        float rs = rsum[qi];
        u16* dst = y2 + ((size_t)((b * 256 + t) * 64 + q)) * 256 + h * 32;
#pragma unroll
        for (int di = 0; di < 2; di++) {
            u32x2 ob = { cvtpk(o_[di][qi][0] * rs, o_[di][qi][1] * rs),
                         cvtpk(o_[di][qi][2] * rs, o_[di][qi][3] * rs) };
            *(u32x2*)&dst[di * 16 + g * 4] = ob;
        }
    }
}

// ---------------- launch ----------------
extern "C" void kernel_launch(void* const* d_in, const int* in_sizes, int n_in,
                              void* d_out, int out_size, void* d_ws, size_t ws_size,
                              hipStream_t stream) {
    const float* x  = (const float*)d_in[0];
    const float* Wa = (const float*)d_in[1];
    const float* Wp = (const float*)d_in[2];
    const float* rt = (const float*)d_in[3];
    const float* rf = (const float*)d_in[4];
    float* out = (float*)d_out;

    u16* planes = (u16*)d_ws;           // 5 planes: q_t,q_f,k_t,k_f,v
    u16* qt  = planes;                  // idxT
    u16* qfp = planes + PL;             // idxF
    u16* ktp = planes + 2 * PL;         // idxT
    u16* kfp = planes + 3 * PL;         // idxF
    u16* vp  = planes + 4 * PL;         // idxT
    u16* y1  = planes + 5 * PL;         // idxF (time-attn out)
    u16* xb  = y1;                      // bf16 x aliases y1 slot (dead before attn_time)
    u16* y2  = ktp;                     // token-major, aliases dead k_t
    float* ct_t = (float*)(planes + 6 * PL);
    float* st_t = ct_t + 8192;
    float* ct_f = st_t + 8192;
    float* st_f = ct_f + 2048;
    u16* wt_a = (u16*)(st_f + 2048);
    u16* wt_p = wt_a + 327680;

    prep_x_k<<<8192, 256, 0, stream>>>(x, xb);
    prep_aux_k<<<394, 256, 0, stream>>>(Wa, Wp, rt, rf, wt_a, wt_p, ct_t, st_t, ct_f, st_f);
    gemm_k<10, true><<<5120, 256, 0, stream>>>(xb, wt_a, planes, nullptr);
    attn_time_k<<<2048, 256, 0, stream>>>(qt, ktp, vp, y1, ct_t, st_t);
    attn_freq_k<<<2048, 256, 0, stream>>>(qfp, kfp, y1, y2, ct_f, st_f);
    gemm_k<2, false><<<1024, 256, 0, stream>>>(y2, wt_p, nullptr, out);
}

// Round 15
// 206.318 us; speedup vs baseline: 2.1119x; 1.0795x over previous
//
#include <hip/hip_runtime.h>

typedef unsigned short u16;
typedef unsigned int u32;
typedef short s16x8 __attribute__((ext_vector_type(8)));
typedef u16 u16x4 __attribute__((ext_vector_type(4)));
typedef float f32x4 __attribute__((ext_vector_type(4)));
typedef u32 u32x2 __attribute__((ext_vector_type(2)));
typedef u32 u32x4 __attribute__((ext_vector_type(4)));

#define MFMA(a,b,c) __builtin_amdgcn_mfma_f32_16x16x32_bf16((a),(b),(c),0,0,0)

static const size_t PL = 16777216;  // elems per [65536][256] plane

__device__ __forceinline__ float b2f(u16 b) {
    return __uint_as_float(((unsigned int)b) << 16);
}
__device__ __forceinline__ u16 f2b(float f) {
    unsigned int u = __float_as_uint(f);
    unsigned int r = (u + 0x7FFFu + ((u >> 16) & 1u)) >> 16;
    return (u16)r;
}
__device__ __forceinline__ u32 cvtpk(float lo, float hi) {
    u32 r;
    asm("v_cvt_pk_bf16_f32 %0, %1, %2" : "=v"(r) : "v"(lo), "v"(hi));
    return r;
}
__device__ __forceinline__ float fexp2(float x) {
#if __has_builtin(__builtin_amdgcn_exp2f)
    return __builtin_amdgcn_exp2f(x);
#else
    return exp2f(x);
#endif
}

// load 8 bf16, apply interleaved-pair rotary in fp32, return bf16x8 (RTNE)
__device__ __forceinline__ s16x8 rot8(const u16* __restrict__ src,
                                      const float* __restrict__ cp,
                                      const float* __restrict__ sp) {
    s16x8 u = *(const s16x8*)src;
    f32x4 c0 = *(const f32x4*)cp, c1 = *(const f32x4*)(cp + 4);
    f32x4 s0 = *(const f32x4*)sp, s1 = *(const f32x4*)(sp + 4);
    float x[8];
#pragma unroll
    for (int j = 0; j < 8; j++) x[j] = b2f((u16)u[j]);
    float c[8] = {c0[0], c0[1], c0[2], c0[3], c1[0], c1[1], c1[2], c1[3]};
    float s[8] = {s0[0], s0[1], s0[2], s0[3], s1[0], s1[1], s1[2], s1[3]};
    u32x4 r;
#pragma unroll
    for (int p = 0; p < 4; p++) {
        float e = x[2 * p], o = x[2 * p + 1];
        float lo = e * c[2 * p] - o * s[2 * p];
        float hi = fmaf(e, s[2 * p + 1], o * c[2 * p + 1]);
        r[p] = cvtpk(lo, hi);
    }
    return __builtin_bit_cast(s16x8, r);
}

// ---------------- fused prep: x->bf16 (blocks 0..8191) + W/rotary (8192..8585) ----
__global__ void prep_all_k(const float* __restrict__ x, u16* __restrict__ xb,
                           const float* __restrict__ Wa, const float* __restrict__ Wp,
                           const float* __restrict__ rt, const float* __restrict__ rf,
                           u16* __restrict__ wt_a, u16* __restrict__ wt_p,
                           float* __restrict__ ct_t, float* __restrict__ st_t,
                           float* __restrict__ ct_f, float* __restrict__ st_f) {
    int blk = blockIdx.x;
    if (blk < 8192) {
        size_t i = ((size_t)blk * 256 + threadIdx.x) * 8;
        f32x4 a = *(const f32x4*)(x + i);
        f32x4 b = *(const f32x4*)(x + i + 4);
        u32x4 o = { cvtpk(a[0], a[1]), cvtpk(a[2], a[3]), cvtpk(b[0], b[1]), cvtpk(b[2], b[3]) };
        *(u32x4*)(xb + i) = o;
        return;
    }
    int i = (blk - 8192) * 256 + threadIdx.x;
    if (i < 81920) {                       // W_attn^T: [1280][256]
        int idx = i * 4;
        int k = idx / 1280, n = idx - k * 1280;
        f32x4 v = *(const f32x4*)&Wa[idx];
#pragma unroll
        for (int j = 0; j < 4; j++) wt_a[(n + j) * 256 + k] = f2b(v[j]);
    } else if (i < 98304) {                // W_proj^T: [256][256]
        int idx = (i - 81920) * 4;
        int k = idx >> 8, n = idx & 255;
        f32x4 v = *(const f32x4*)&Wp[idx];
#pragma unroll
        for (int j = 0; j < 4; j++) wt_p[(n + j) * 256 + k] = f2b(v[j]);
    } else if (i < 100352) {               // rotary_t tables (256*32)
        int j = (i - 98304) * 4;
        f32x4 v = *(const f32x4*)&rt[j];
        f32x4 c, s;
#pragma unroll
        for (int jj = 0; jj < 4; jj++) { float ss, cc; __sincosf(v[jj], &ss, &cc); c[jj] = cc; s[jj] = ss; }
        *(f32x4*)&ct_t[j] = c; *(f32x4*)&st_t[j] = s;
    } else if (i < 100864) {               // rotary_f tables (64*32)
        int j = (i - 100352) * 4;
        f32x4 v = *(const f32x4*)&rf[j];
        f32x4 c, s;
#pragma unroll
        for (int jj = 0; jj < 4; jj++) { float ss, cc; __sincosf(v[jj], &ss, &cc); c[jj] = cc; s[jj] = ss; }
        *(f32x4*)&ct_f[j] = c; *(f32x4*)&st_f[j] = s;
    }
}

// ---------------- GEMM: C^T = Bt * A^T, A[M][256] bf16, Bt[N][256] bf16 ----------
// 1D grid, XCD-chunked swizzle (bijective): 512 M-tiles x NT N-tiles, N fastest.
// ALL global loads issued in prologue; BK=64 double-buffered LDS, unrolled.
// TO_PLANES: scatter bf16 into 5 attention-layout planes; else fp32 out[M][256]
template<int NT, bool TO_PLANES>
__global__ __launch_bounds__(256, 2) void gemm_k(const u16* __restrict__ A,
                                                 const u16* __restrict__ Bt,
                                                 u16* __restrict__ outp,
                                                 float* __restrict__ outf) {
    __shared__ __align__(16) u16 As[2][128][72];
    __shared__ __align__(16) u16 Bs[2][128][72];
    int bid = blockIdx.x;
    int xcd = bid & 7, slot = bid >> 3;
    int L = xcd * ((512 * NT) / 8) + slot;
    int mt = L / NT, nt = L - mt * NT;
    int m0 = mt * 128, n0 = nt * 128;
    int tid = threadIdx.x, lane = tid & 63, w = tid >> 6;
    int wm = w >> 1, wn = w & 1;
    int g = lane >> 4, lr = lane & 15;
    f32x4 acc[4][4] = {};   // acc[ni][mi] = C^T block
    s16x8 apb[4][4], bpb[4][4];   // [chunk][i] staging, all issued upfront

    auto loadAB = [&](int ch) {
#pragma unroll
        for (int i = 0; i < 4; i++) {
            int c = tid + i * 256, row = c >> 3, p = (c & 7) * 8;
            apb[ch][i] = *(const s16x8*)&A[(size_t)(m0 + row) * 256 + ch * 64 + p];
            bpb[ch][i] = *(const s16x8*)&Bt[(size_t)(n0 + row) * 256 + ch * 64 + p];
        }
    };
    auto storeAB = [&](int buf, int ch) {
#pragma unroll
        for (int i = 0; i < 4; i++) {
            int c = tid + i * 256, row = c >> 3, p = (c & 7) * 8;
            *(s16x8*)&As[buf][row][p] = apb[ch][i];
            *(s16x8*)&Bs[buf][row][p] = bpb[ch][i];
        }
    };

    // prologue: issue ALL loads; stage chunk 0
    loadAB(0); loadAB(1); loadAB(2); loadAB(3);
    storeAB(0, 0);
    __syncthreads();

#pragma unroll
    for (int s = 0; s < 4; s++) {
        int cur = s & 1;
        s16x8 af0[4], bf0[4];
#pragma unroll
        for (int mi = 0; mi < 4; mi++) af0[mi] = *(const s16x8*)&As[cur][wm * 64 + mi * 16 + lr][g * 8];
#pragma unroll
        for (int ni = 0; ni < 4; ni++) bf0[ni] = *(const s16x8*)&Bs[cur][wn * 64 + ni * 16 + lr][g * 8];
        if (s < 3) storeAB(cur ^ 1, s + 1);
#pragma unroll
        for (int ni = 0; ni < 4; ni++)
#pragma unroll
            for (int mi = 0; mi < 4; mi++)
                acc[ni][mi] = MFMA(bf0[ni], af0[mi], acc[ni][mi]);
        s16x8 af1[4], bf1[4];
#pragma unroll
        for (int mi = 0; mi < 4; mi++) af1[mi] = *(const s16x8*)&As[cur][wm * 64 + mi * 16 + lr][32 + g * 8];
#pragma unroll
        for (int ni = 0; ni < 4; ni++) bf1[ni] = *(const s16x8*)&Bs[cur][wn * 64 + ni * 16 + lr][32 + g * 8];
#pragma unroll
        for (int ni = 0; ni < 4; ni++)
#pragma unroll
            for (int mi = 0; mi < 4; mi++)
                acc[ni][mi] = MFMA(bf1[ni], af1[mi], acc[ni][mi]);
        __syncthreads();
    }

#pragma unroll
    for (int ni = 0; ni < 4; ni++) {
#pragma unroll
        for (int mi = 0; mi < 4; mi++) {
            int token = m0 + wm * 64 + mi * 16 + lr;
            int n = n0 + wn * 64 + ni * 16 + g * 4;
            if (TO_PLANES) {
                u32x2 pk = { cvtpk(acc[ni][mi][0], acc[ni][mi][1]),
                             cvtpk(acc[ni][mi][2], acc[ni][mi][3]) };
                int pl = n >> 8, c = n & 255, h = c >> 5, d0 = c & 31;
                int b = token >> 14, t = (token >> 6) & 255, f = token & 63;
                size_t addr = (pl == 1 || pl == 3)
                    ? ((size_t)(((b * 256 + t) * 8 + h) * 64 + f) * 32 + d0)
                    : ((size_t)(((b * 64 + f) * 8 + h) * 256 + t) * 32 + d0);
                *(u32x2*)&outp[(size_t)pl * PL + addr] = pk;
            } else {
                *(f32x4*)&outf[(size_t)token * 256 + n] = acc[ni][mi];
            }
        }
    }
}

// ---------------- time attention: one block per head (b,f,h); keys t=256 ----------
// K/V staged+rotated ONCE, then both q-halves processed in-block.
// layouts: q_t/k_t/v head-major idxT: head*8192 + t*32 + d ; y1 idxF
__global__ __launch_bounds__(256, 3) void attn_time_k(const u16* __restrict__ qt,
                                                      const u16* __restrict__ kt,
                                                      const u16* __restrict__ vp,
                                                      u16* __restrict__ y1,
                                                      const float* __restrict__ ct,
                                                      const float* __restrict__ st) {
    __shared__ __align__(16) u16 K_l[256][40];
    __shared__ __align__(16) u16 Vt[32][264];
    __shared__ __align__(16) u16 Pst[4][2][16][40];
    int bid = blockIdx.x;
    int xcd = bid & 7, slot = bid >> 3;
    int head = xcd * 256 + slot;                   // head = (b*64+f)*8+h, 2048 total
    int h = head & 7, f = (head >> 3) & 63, b = head >> 9;
    int tid = threadIdx.x, lane = tid & 63, w = tid >> 6;
    int g = lane >> 4, lr = lane & 15;
    const u16* Khead = kt + (size_t)head * 8192;
    const u16* Qhead = qt + (size_t)head * 8192;
    const u16* Vhead = vp + (size_t)head * 8192;

    // stage K (rotated), coalesced: chunk c -> row c>>2, part c&3
#pragma unroll
    for (int i = 0; i < 4; i++) {
        int c = tid + i * 256;
        int t = c >> 2, p = (c & 3) * 8;
        *(s16x8*)&K_l[t][p] = rot8(Khead + t * 32 + p, ct + t * 32 + p, st + t * 32 + p);
    }
    // stage V^T
    {
        int ka = (tid & 63) * 4, db = (tid >> 6) * 8;
        const u16* vb = Vhead + (size_t)ka * 32 + db;
        s16x8 r0 = *(const s16x8*)(vb);
        s16x8 r1 = *(const s16x8*)(vb + 32);
        s16x8 r2 = *(const s16x8*)(vb + 64);
        s16x8 r3 = *(const s16x8*)(vb + 96);
#pragma unroll
        for (int dd = 0; dd < 8; dd++) {
            u16x4 pk = { (u16)r0[dd], (u16)r1[dd], (u16)r2[dd], (u16)r3[dd] };
            *(u16x4*)&Vt[db + dd][ka] = pk;
        }
    }
    __syncthreads();

    const float sc2 = 0.17677669529663687f * 1.4426950408889634f;  // scale*log2e
    for (int qh = 0; qh < 2; qh++) {
        // Q fragments (rotated); wave owns q rows [qbase, qbase+32)
        int qbase = qh * 128 + w * 32;
        s16x8 qf_[2];
#pragma unroll
        for (int qi = 0; qi < 2; qi++) {
            int q = qbase + qi * 16 + lr;
            qf_[qi] = rot8(Qhead + q * 32 + g * 8, ct + q * 32 + g * 8, st + q * 32 + g * 8);
        }

        // S^T[key][q]
        f32x4 sT[16][2] = {};
#pragma unroll
        for (int ki = 0; ki < 16; ki++) {
            s16x8 kf8 = *(const s16x8*)&K_l[ki * 16 + lr][g * 8];
            sT[ki][0] = MFMA(kf8, qf_[0], sT[ki][0]);
            sT[ki][1] = MFMA(kf8, qf_[1], sT[ki][1]);
        }
        float rsum[2];
#pragma unroll
        for (int qi = 0; qi < 2; qi++) {
            float m = -1e30f;
#pragma unroll
            for (int ki = 0; ki < 16; ki++)
#pragma unroll
                for (int r = 0; r < 4; r++) m = fmaxf(m, sT[ki][qi][r]);
            m = fmaxf(m, __shfl_xor(m, 16));
            m = fmaxf(m, __shfl_xor(m, 32));
            float msc = m * sc2;
            float ssum = 0.f;
#pragma unroll
            for (int ki = 0; ki < 16; ki++)
#pragma unroll
                for (int r = 0; r < 4; r++) {
                    float p = fexp2(sT[ki][qi][r] * sc2 - msc);
                    sT[ki][qi][r] = p; ssum += p;
                }
            ssum += __shfl_xor(ssum, 16);
            ssum += __shfl_xor(ssum, 32);
            rsum[qi] = 1.0f / ssum;
        }

        // O^T[d][q] via per-wave streaming P^T redistribution (no barrier)
        f32x4 o_[2][2] = {};
#pragma unroll
        for (int ks = 0; ks < 8; ks++) {
            s16x8 vf0 = *(const s16x8*)&Vt[lr][ks * 32 + g * 8];
            s16x8 vf1 = *(const s16x8*)&Vt[16 + lr][ks * 32 + g * 8];
#pragma unroll
            for (int qi = 0; qi < 2; qi++) {
                u32x2 w0 = { cvtpk(sT[2 * ks][qi][0], sT[2 * ks][qi][1]),
                             cvtpk(sT[2 * ks][qi][2], sT[2 * ks][qi][3]) };
                u32x2 w1 = { cvtpk(sT[2 * ks + 1][qi][0], sT[2 * ks + 1][qi][1]),
                             cvtpk(sT[2 * ks + 1][qi][2], sT[2 * ks + 1][qi][3]) };
                *(u32x2*)&Pst[w][qi][lr][g * 4] = w0;
                *(u32x2*)&Pst[w][qi][lr][16 + g * 4] = w1;
                s16x8 pf = *(const s16x8*)&Pst[w][qi][lr][g * 8];
                o_[0][qi] = MFMA(vf0, pf, o_[0][qi]);
                o_[1][qi] = MFMA(vf1, pf, o_[1][qi]);
            }
        }
#pragma unroll
        for (int qi = 0; qi < 2; qi++) {
            int q = qbase + qi * 16 + lr;
            float rs = rsum[qi];
            u16* dst = y1 + ((size_t)(((b * 256 + q) * 8 + h) * 64 + f)) * 32;
#pragma unroll
            for (int di = 0; di < 2; di++) {
                u32x2 ob = { cvtpk(o_[di][qi][0] * rs, o_[di][qi][1] * rs),
                             cvtpk(o_[di][qi][2] * rs, o_[di][qi][3] * rs) };
                *(u32x2*)&dst[di * 16 + g * 4] = ob;
            }
        }
    }
}

// ---------------- frequency attention: wave per head (b,t,h); keys f=64 ----------
// q_f/k_f/y1 idxF: head*2048 + f*32 + d ; y2 token-major
__global__ __launch_bounds__(256, 3) void attn_freq_k(const u16* __restrict__ qfp,
                                                      const u16* __restrict__ kfp,
                                                      const u16* __restrict__ y1,
                                                      u16* __restrict__ y2,
                                                      const float* __restrict__ ct,
                                                      const float* __restrict__ st) {
    __shared__ __align__(16) u16 K_l[4][64][40];
    __shared__ __align__(16) u16 Vt[4][32][72];
    __shared__ __align__(16) u16 Pst[4][2][16][40];
    int tid = threadIdx.x, lane = tid & 63, w = tid >> 6;
    int g = lane >> 4, lr = lane & 15;
    int head = blockIdx.x * 4 + w;                 // head = (b*256+t)*8+h
    int h = head & 7, t = (head >> 3) & 255, b = head >> 11;
    const u16* Khead = kfp + (size_t)head * 2048;
    const u16* Qhead = qfp + (size_t)head * 2048;
    const u16* Vhead = y1 + (size_t)head * 2048;

    // stage K (rotated)
#pragma unroll
    for (int i = 0; i < 4; i++) {
        int c = i * 64 + lane;
        int row = c >> 2, p = (c & 3) * 8;
        *(s16x8*)&K_l[w][row][p] = rot8(Khead + row * 32 + p, ct + row * 32 + p, st + row * 32 + p);
    }
    // stage V^T (per-wave; same-wave DS ordering -> no barrier)
    {
        int ka = lr * 4, db = g * 8;
        const u16* vb = Vhead + (size_t)ka * 32 + db;
        s16x8 r0 = *(const s16x8*)(vb);
        s16x8 r1 = *(const s16x8*)(vb + 32);
        s16x8 r2 = *(const s16x8*)(vb + 64);
        s16x8 r3 = *(const s16x8*)(vb + 96);
#pragma unroll
        for (int dd = 0; dd < 8; dd++) {
            u16x4 pk = { (u16)r0[dd], (u16)r1[dd], (u16)r2[dd], (u16)r3[dd] };
            *(u16x4*)&Vt[w][db + dd][ka] = pk;
        }
    }
    s16x8 qfr[4];
#pragma unroll
    for (int qi = 0; qi < 4; qi++) {
        int q = qi * 16 + lr;
        qfr[qi] = rot8(Qhead + q * 32 + g * 8, ct + q * 32 + g * 8, st + q * 32 + g * 8);
    }
    // per-wave LDS only -> no __syncthreads needed

    f32x4 sT[4][4] = {};
#pragma unroll
    for (int ki = 0; ki < 4; ki++) {
        s16x8 kf8 = *(const s16x8*)&K_l[w][ki * 16 + lr][g * 8];
#pragma unroll
        for (int qi = 0; qi < 4; qi++) sT[ki][qi] = MFMA(kf8, qfr[qi], sT[ki][qi]);
    }
    const float sc2 = 0.17677669529663687f * 1.4426950408889634f;
    float rsum[4];
#pragma unroll
    for (int qi = 0; qi < 4; qi++) {
        float m = -1e30f;
#pragma unroll
        for (int ki = 0; ki < 4; ki++)
#pragma unroll
            for (int r = 0; r < 4; r++) m = fmaxf(m, sT[ki][qi][r]);
        m = fmaxf(m, __shfl_xor(m, 16));
        m = fmaxf(m, __shfl_xor(m, 32));
        float msc = m * sc2;
        float ssum = 0.f;
#pragma unroll
        for (int ki = 0; ki < 4; ki++)
#pragma unroll
            for (int r = 0; r < 4; r++) {
                float p = fexp2(sT[ki][qi][r] * sc2 - msc);
                sT[ki][qi][r] = p; ssum += p;
            }
        ssum += __shfl_xor(ssum, 16);
        ssum += __shfl_xor(ssum, 32);
        rsum[qi] = 1.0f / ssum;
    }

    f32x4 o_[2][4] = {};
#pragma unroll
    for (int ks = 0; ks < 2; ks++) {
        s16x8 vf0 = *(const s16x8*)&Vt[w][lr][ks * 32 + g * 8];
        s16x8 vf1 = *(const s16x8*)&Vt[w][16 + lr][ks * 32 + g * 8];
#pragma unroll
        for (int qi = 0; qi < 4; qi++) {
            u32x2 w0 = { cvtpk(sT[2 * ks][qi][0], sT[2 * ks][qi][1]),
                         cvtpk(sT[2 * ks][qi][2], sT[2 * ks][qi][3]) };
            u32x2 w1 = { cvtpk(sT[2 * ks + 1][qi][0], sT[2 * ks + 1][qi][1]),
                         cvtpk(sT[2 * ks + 1][qi][2], sT[2 * ks + 1][qi][3]) };
            *(u32x2*)&Pst[w][qi & 1][lr][g * 4] = w0;
            *(u32x2*)&Pst[w][qi & 1][lr][16 + g * 4] = w1;
            s16x8 pf = *(const s16x8*)&Pst[w][qi & 1][lr][g * 8];
            o_[0][qi] = MFMA(vf0, pf, o_[0][qi]);
            o_[1][qi] = MFMA(vf1, pf, o_[1][qi]);
        }
    }
#pragma unroll
    for (int qi = 0; qi < 4; qi++) {
        int q = qi * 16 + lr;
        float rs = rsum[qi];
        u16* dst = y2 + ((size_t)((b * 256 + t) * 64 + q)) * 256 + h * 32;
#pragma unroll
        for (int di = 0; di < 2; di++) {
            u32x2 ob = { cvtpk(o_[di][qi][0] * rs, o_[di][qi][1] * rs),
                         cvtpk(o_[di][qi][2] * rs, o_[di][qi][3] * rs) };
            *(u32x2*)&dst[di * 16 + g * 4] = ob;
        }
    }
}

// ---------------- launch ----------------
extern "C" void kernel_launch(void* const* d_in, const int* in_sizes, int n_in,
                              void* d_out, int out_size, void* d_ws, size_t ws_size,
                              hipStream_t stream) {
    const float* x  = (const float*)d_in[0];
    const float* Wa = (const float*)d_in[1];
    const float* Wp = (const float*)d_in[2];
    const float* rt = (const float*)d_in[3];
    const float* rf = (const float*)d_in[4];
    float* out = (float*)d_out;

    u16* planes = (u16*)d_ws;           // 5 planes: q_t,q_f,k_t,k_f,v
    u16* qt  = planes;                  // idxT
    u16* qfp = planes + PL;             // idxF
    u16* ktp = planes + 2 * PL;         // idxT
    u16* kfp = planes + 3 * PL;         // idxF
    u16* vp  = planes + 4 * PL;         // idxT
    u16* y1  = planes + 5 * PL;         // idxF (time-attn out)
    u16* xb  = y1;                      // bf16 x aliases y1 slot (dead before attn_time)
    u16* y2  = ktp;                     // token-major, aliases dead k_t
    float* ct_t = (float*)(planes + 6 * PL);
    float* st_t = ct_t + 8192;
    float* ct_f = st_t + 8192;
    float* st_f = ct_f + 2048;
    u16* wt_a = (u16*)(st_f + 2048);
    u16* wt_p = wt_a + 327680;

    prep_all_k<<<8586, 256, 0, stream>>>(x, xb, Wa, Wp, rt, rf, wt_a, wt_p,
                                         ct_t, st_t, ct_f, st_f);
    gemm_k<10, true><<<5120, 256, 0, stream>>>(xb, wt_a, planes, nullptr);
    attn_time_k<<<2048, 256, 0, stream>>>(qt, ktp, vp, y1, ct_t, st_t);
    attn_freq_k<<<2048, 256, 0, stream>>>(qfp, kfp, y1, y2, ct_f, st_f);
    gemm_k<2, false><<<1024, 256, 0, stream>>>(y2, wt_p, nullptr, out);
}

// Round 17
// 205.909 us; speedup vs baseline: 2.1161x; 1.0020x over previous
//
#include <hip/hip_runtime.h>

typedef unsigned short u16;
typedef unsigned int u32;
typedef short s16x8 __attribute__((ext_vector_type(8)));
typedef u16 u16x4 __attribute__((ext_vector_type(4)));
typedef float f32x4 __attribute__((ext_vector_type(4)));
typedef u32 u32x2 __attribute__((ext_vector_type(2)));
typedef u32 u32x4 __attribute__((ext_vector_type(4)));

#define MFMA(a,b,c) __builtin_amdgcn_mfma_f32_16x16x32_bf16((a),(b),(c),0,0,0)

static const size_t PL = 16777216;  // elems per [65536][256] plane

__device__ __forceinline__ float b2f(u16 b) {
    return __uint_as_float(((unsigned int)b) << 16);
}
__device__ __forceinline__ u16 f2b(float f) {
    unsigned int u = __float_as_uint(f);
    unsigned int r = (u + 0x7FFFu + ((u >> 16) & 1u)) >> 16;
    return (u16)r;
}
__device__ __forceinline__ u32 cvtpk(float lo, float hi) {
    u32 r;
    asm("v_cvt_pk_bf16_f32 %0, %1, %2" : "=v"(r) : "v"(lo), "v"(hi));
    return r;
}
__device__ __forceinline__ float fexp2(float x) {
#if __has_builtin(__builtin_amdgcn_exp2f)
    return __builtin_amdgcn_exp2f(x);
#else
    return exp2f(x);
#endif
}

// load 8 bf16, apply interleaved-pair rotary in fp32, return bf16x8 (RTNE)
__device__ __forceinline__ s16x8 rot8(const u16* __restrict__ src,
                                      const float* __restrict__ cp,
                                      const float* __restrict__ sp) {
    s16x8 u = *(const s16x8*)src;
    f32x4 c0 = *(const f32x4*)cp, c1 = *(const f32x4*)(cp + 4);
    f32x4 s0 = *(const f32x4*)sp, s1 = *(const f32x4*)(sp + 4);
    float x[8];
#pragma unroll
    for (int j = 0; j < 8; j++) x[j] = b2f((u16)u[j]);
    float c[8] = {c0[0], c0[1], c0[2], c0[3], c1[0], c1[1], c1[2], c1[3]};
    float s[8] = {s0[0], s0[1], s0[2], s0[3], s1[0], s1[1], s1[2], s1[3]};
    u32x4 r;
#pragma unroll
    for (int p = 0; p < 4; p++) {
        float e = x[2 * p], o = x[2 * p + 1];
        float lo = e * c[2 * p] - o * s[2 * p];
        float hi = fmaf(e, s[2 * p + 1], o * c[2 * p + 1]);
        r[p] = cvtpk(lo, hi);
    }
    return __builtin_bit_cast(s16x8, r);
}

// ---------------- fused prep: x->bf16 (blocks 0..8191) + W/rotary (8192..8585) ----
__global__ void prep_all_k(const float* __restrict__ x, u16* __restrict__ xb,
                           const float* __restrict__ Wa, const float* __restrict__ Wp,
                           const float* __restrict__ rt, const float* __restrict__ rf,
                           u16* __restrict__ wt_a, u16* __restrict__ wt_p,
                           float* __restrict__ ct_t, float* __restrict__ st_t,
                           float* __restrict__ ct_f, float* __restrict__ st_f) {
    int blk = blockIdx.x;
    if (blk < 8192) {
        size_t i = ((size_t)blk * 256 + threadIdx.x) * 8;
        f32x4 a = *(const f32x4*)(x + i);
        f32x4 b = *(const f32x4*)(x + i + 4);
        u32x4 o = { cvtpk(a[0], a[1]), cvtpk(a[2], a[3]), cvtpk(b[0], b[1]), cvtpk(b[2], b[3]) };
        *(u32x4*)(xb + i) = o;
        return;
    }
    int i = (blk - 8192) * 256 + threadIdx.x;
    if (i < 81920) {                       // W_attn^T: [1280][256]
        int idx = i * 4;
        int k = idx / 1280, n = idx - k * 1280;
        f32x4 v = *(const f32x4*)&Wa[idx];
#pragma unroll
        for (int j = 0; j < 4; j++) wt_a[(n + j) * 256 + k] = f2b(v[j]);
    } else if (i < 98304) {                // W_proj^T: [256][256]
        int idx = (i - 81920) * 4;
        int k = idx >> 8, n = idx & 255;
        f32x4 v = *(const f32x4*)&Wp[idx];
#pragma unroll
        for (int j = 0; j < 4; j++) wt_p[(n + j) * 256 + k] = f2b(v[j]);
    } else if (i < 100352) {               // rotary_t tables (256*32)
        int j = (i - 98304) * 4;
        f32x4 v = *(const f32x4*)&rt[j];
        f32x4 c, s;
#pragma unroll
        for (int jj = 0; jj < 4; jj++) { float ss, cc; __sincosf(v[jj], &ss, &cc); c[jj] = cc; s[jj] = ss; }
        *(f32x4*)&ct_t[j] = c; *(f32x4*)&st_t[j] = s;
    } else if (i < 100864) {               // rotary_f tables (64*32)
        int j = (i - 100352) * 4;
        f32x4 v = *(const f32x4*)&rf[j];
        f32x4 c, s;
#pragma unroll
        for (int jj = 0; jj < 4; jj++) { float ss, cc; __sincosf(v[jj], &ss, &cc); c[jj] = cc; s[jj] = ss; }
        *(f32x4*)&ct_f[j] = c; *(f32x4*)&st_f[j] = s;
    }
}

// ---------------- GEMM: C^T = Bt * A^T, A[M][256] bf16, Bt[N][256] bf16 ----------
// 1D grid, XCD-chunked swizzle (bijective): 512 M-tiles x NT N-tiles, N fastest.
// ALL global loads issued in prologue; BK=64 double-buffered LDS, unrolled.
// TO_PLANES: scatter bf16 into 5 attention-layout planes; else fp32 out[M][256]
template<int NT, bool TO_PLANES>
__global__ __launch_bounds__(256, 2) void gemm_k(const u16* __restrict__ A,
                                                 const u16* __restrict__ Bt,
                                                 u16* __restrict__ outp,
                                                 float* __restrict__ outf) {
    __shared__ __align__(16) u16 As[2][128][72];
    __shared__ __align__(16) u16 Bs[2][128][72];
    int bid = blockIdx.x;
    int xcd = bid & 7, slot = bid >> 3;
    int L = xcd * ((512 * NT) / 8) + slot;
    int mt = L / NT, nt = L - mt * NT;
    int m0 = mt * 128, n0 = nt * 128;
    int tid = threadIdx.x, lane = tid & 63, w = tid >> 6;
    int wm = w >> 1, wn = w & 1;
    int g = lane >> 4, lr = lane & 15;
    f32x4 acc[4][4] = {};   // acc[ni][mi] = C^T block
    s16x8 apb[4][4], bpb[4][4];   // [chunk][i] staging, all issued upfront

    auto loadAB = [&](int ch) {
#pragma unroll
        for (int i = 0; i < 4; i++) {
            int c = tid + i * 256, row = c >> 3, p = (c & 7) * 8;
            apb[ch][i] = *(const s16x8*)&A[(size_t)(m0 + row) * 256 + ch * 64 + p];
            bpb[ch][i] = *(const s16x8*)&Bt[(size_t)(n0 + row) * 256 + ch * 64 + p];
        }
    };
    auto storeAB = [&](int buf, int ch) {
#pragma unroll
        for (int i = 0; i < 4; i++) {
            int c = tid + i * 256, row = c >> 3, p = (c & 7) * 8;
            *(s16x8*)&As[buf][row][p] = apb[ch][i];
            *(s16x8*)&Bs[buf][row][p] = bpb[ch][i];
        }
    };

    // prologue: issue ALL loads; stage chunk 0
    loadAB(0); loadAB(1); loadAB(2); loadAB(3);
    storeAB(0, 0);
    __syncthreads();

#pragma unroll
    for (int s = 0; s < 4; s++) {
        int cur = s & 1;
        s16x8 af0[4], bf0[4];
#pragma unroll
        for (int mi = 0; mi < 4; mi++) af0[mi] = *(const s16x8*)&As[cur][wm * 64 + mi * 16 + lr][g * 8];
#pragma unroll
        for (int ni = 0; ni < 4; ni++) bf0[ni] = *(const s16x8*)&Bs[cur][wn * 64 + ni * 16 + lr][g * 8];
        if (s < 3) storeAB(cur ^ 1, s + 1);
#pragma unroll
        for (int ni = 0; ni < 4; ni++)
#pragma unroll
            for (int mi = 0; mi < 4; mi++)
                acc[ni][mi] = MFMA(bf0[ni], af0[mi], acc[ni][mi]);
        s16x8 af1[4], bf1[4];
#pragma unroll
        for (int mi = 0; mi < 4; mi++) af1[mi] = *(const s16x8*)&As[cur][wm * 64 + mi * 16 + lr][32 + g * 8];
#pragma unroll
        for (int ni = 0; ni < 4; ni++) bf1[ni] = *(const s16x8*)&Bs[cur][wn * 64 + ni * 16 + lr][32 + g * 8];
#pragma unroll
        for (int ni = 0; ni < 4; ni++)
#pragma unroll
            for (int mi = 0; mi < 4; mi++)
                acc[ni][mi] = MFMA(bf1[ni], af1[mi], acc[ni][mi]);
        __syncthreads();
    }

#pragma unroll
    for (int ni = 0; ni < 4; ni++) {
#pragma unroll
        for (int mi = 0; mi < 4; mi++) {
            int token = m0 + wm * 64 + mi * 16 + lr;
            int n = n0 + wn * 64 + ni * 16 + g * 4;
            if (TO_PLANES) {
                u32x2 pk = { cvtpk(acc[ni][mi][0], acc[ni][mi][1]),
                             cvtpk(acc[ni][mi][2], acc[ni][mi][3]) };
                int pl = n >> 8, c = n & 255, h = c >> 5, d0 = c & 31;
                int b = token >> 14, t = (token >> 6) & 255, f = token & 63;
                size_t addr = (pl == 1 || pl == 3)
                    ? ((size_t)(((b * 256 + t) * 8 + h) * 64 + f) * 32 + d0)
                    : ((size_t)(((b * 64 + f) * 8 + h) * 256 + t) * 32 + d0);
                *(u32x2*)&outp[(size_t)pl * PL + addr] = pk;
            } else {
                *(f32x4*)&outf[(size_t)token * 256 + n] = acc[ni][mi];
            }
        }
    }
}

// ---------------- time attention: one block per head (b,f,h); keys t=256 ----------
// K/V staged+rotated ONCE, then both q-halves processed in-block.
// layouts: q_t/k_t/v head-major idxT: head*8192 + t*32 + d ; y1 idxF
__global__ __launch_bounds__(256, 3) void attn_time_k(const u16* __restrict__ qt,
                                                      const u16* __restrict__ kt,
                                                      const u16* __restrict__ vp,
                                                      u16* __restrict__ y1,
                                                      const float* __restrict__ ct,
                                                      const float* __restrict__ st) {
    __shared__ __align__(16) u16 K_l[256][40];
    __shared__ __align__(16) u16 Vt[32][264];
    __shared__ __align__(16) u16 Pst[4][2][16][40];
    int bid = blockIdx.x;
    int xcd = bid & 7, slot = bid >> 3;
    int head = xcd * 256 + slot;                   // head = (b*64+f)*8+h, 2048 total
    int h = head & 7, f = (head >> 3) & 63, b = head >> 9;
    int tid = threadIdx.x, lane = tid & 63, w = tid >> 6;
    int g = lane >> 4, lr = lane & 15;
    const u16* Khead = kt + (size_t)head * 8192;
    const u16* Qhead = qt + (size_t)head * 8192;
    const u16* Vhead = vp + (size_t)head * 8192;

    // stage K (rotated), coalesced: chunk c -> row c>>2, part c&3
#pragma unroll
    for (int i = 0; i < 4; i++) {
        int c = tid + i * 256;
        int t = c >> 2, p = (c & 3) * 8;
        *(s16x8*)&K_l[t][p] = rot8(Khead + t * 32 + p, ct + t * 32 + p, st + t * 32 + p);
    }
    // stage V^T
    {
        int ka = (tid & 63) * 4, db = (tid >> 6) * 8;
        const u16* vb = Vhead + (size_t)ka * 32 + db;
        s16x8 r0 = *(const s16x8*)(vb);
        s16x8 r1 = *(const s16x8*)(vb + 32);
        s16x8 r2 = *(const s16x8*)(vb + 64);
        s16x8 r3 = *(const s16x8*)(vb + 96);
#pragma unroll
        for (int dd = 0; dd < 8; dd++) {
            u16x4 pk = { (u16)r0[dd], (u16)r1[dd], (u16)r2[dd], (u16)r3[dd] };
            *(u16x4*)&Vt[db + dd][ka] = pk;
        }
    }
    __syncthreads();

    const float sc2 = 0.17677669529663687f * 1.4426950408889634f;  // scale*log2e
    for (int qh = 0; qh < 2; qh++) {
        // Q fragments (rotated); wave owns q rows [qbase, qbase+32)
        int qbase = qh * 128 + w * 32;
        s16x8 qf_[2];
#pragma unroll
        for (int qi = 0; qi < 2; qi++) {
            int q = qbase + qi * 16 + lr;
            qf_[qi] = rot8(Qhead + q * 32 + g * 8, ct + q * 32 + g * 8, st + q * 32 + g * 8);
        }

        // S^T[key][q]
        f32x4 sT[16][2] = {};
#pragma unroll
        for (int ki = 0; ki < 16; ki++) {
            s16x8 kf8 = *(const s16x8*)&K_l[ki * 16 + lr][g * 8];
            sT[ki][0] = MFMA(kf8, qf_[0], sT[ki][0]);
            sT[ki][1] = MFMA(kf8, qf_[1], sT[ki][1]);
        }
        float rsum[2];
#pragma unroll
        for (int qi = 0; qi < 2; qi++) {
            float m = -1e30f;
#pragma unroll
            for (int ki = 0; ki < 16; ki++)
#pragma unroll
                for (int r = 0; r < 4; r++) m = fmaxf(m, sT[ki][qi][r]);
            m = fmaxf(m, __shfl_xor(m, 16));
            m = fmaxf(m, __shfl_xor(m, 32));
            float msc = m * sc2;
            float ssum = 0.f;
#pragma unroll
            for (int ki = 0; ki < 16; ki++)
#pragma unroll
                for (int r = 0; r < 4; r++) {
                    float p = fexp2(sT[ki][qi][r] * sc2 - msc);
                    sT[ki][qi][r] = p; ssum += p;
                }
            ssum += __shfl_xor(ssum, 16);
            ssum += __shfl_xor(ssum, 32);
            rsum[qi] = 1.0f / ssum;
        }

        // O^T[d][q] via per-wave streaming P^T redistribution (no barrier)
        f32x4 o_[2][2] = {};
#pragma unroll
        for (int ks = 0; ks < 8; ks++) {
            s16x8 vf0 = *(const s16x8*)&Vt[lr][ks * 32 + g * 8];
            s16x8 vf1 = *(const s16x8*)&Vt[16 + lr][ks * 32 + g * 8];
#pragma unroll
            for (int qi = 0; qi < 2; qi++) {
                u32x2 w0 = { cvtpk(sT[2 * ks][qi][0], sT[2 * ks][qi][1]),
                             cvtpk(sT[2 * ks][qi][2], sT[2 * ks][qi][3]) };
                u32x2 w1 = { cvtpk(sT[2 * ks + 1][qi][0], sT[2 * ks + 1][qi][1]),
                             cvtpk(sT[2 * ks + 1][qi][2], sT[2 * ks + 1][qi][3]) };
                *(u32x2*)&Pst[w][qi][lr][g * 4] = w0;
                *(u32x2*)&Pst[w][qi][lr][16 + g * 4] = w1;
                s16x8 pf = *(const s16x8*)&Pst[w][qi][lr][g * 8];
                o_[0][qi] = MFMA(vf0, pf, o_[0][qi]);
                o_[1][qi] = MFMA(vf1, pf, o_[1][qi]);
            }
        }
#pragma unroll
        for (int qi = 0; qi < 2; qi++) {
            int q = qbase + qi * 16 + lr;
            float rs = rsum[qi];
            u16* dst = y1 + ((size_t)(((b * 256 + q) * 8 + h) * 64 + f)) * 32;
#pragma unroll
            for (int di = 0; di < 2; di++) {
                u32x2 ob = { cvtpk(o_[di][qi][0] * rs, o_[di][qi][1] * rs),
                             cvtpk(o_[di][qi][2] * rs, o_[di][qi][3] * rs) };
                *(u32x2*)&dst[di * 16 + g * 4] = ob;
            }
        }
    }
}

// ---------------- frequency attention: wave per head (b,t,h); keys f=64 ----------
// q_f/k_f/y1 idxF: head*2048 + f*32 + d ; y2 token-major
__global__ __launch_bounds__(256, 3) void attn_freq_k(const u16* __restrict__ qfp,
                                                      const u16* __restrict__ kfp,
                                                      const u16* __restrict__ y1,
                                                      u16* __restrict__ y2,
                                                      const float* __restrict__ ct,
                                                      const float* __restrict__ st) {
    __shared__ __align__(16) u16 K_l[4][64][40];
    __shared__ __align__(16) u16 Vt[4][32][72];
    __shared__ __align__(16) u16 Pst[4][2][16][40];
    int tid = threadIdx.x, lane = tid & 63, w = tid >> 6;
    int g = lane >> 4, lr = lane & 15;
    int head = blockIdx.x * 4 + w;                 // head = (b*256+t)*8+h
    int h = head & 7, t = (head >> 3) & 255, b = head >> 11;
    const u16* Khead = kfp + (size_t)head * 2048;
    const u16* Qhead = qfp + (size_t)head * 2048;
    const u16* Vhead = y1 + (size_t)head * 2048;

    // stage K (rotated)
#pragma unroll
    for (int i = 0; i < 4; i++) {
        int c = i * 64 + lane;
        int row = c >> 2, p = (c & 3) * 8;
        *(s16x8*)&K_l[w][row][p] = rot8(Khead + row * 32 + p, ct + row * 32 + p, st + row * 32 + p);
    }
    // stage V^T (per-wave; same-wave DS ordering -> no barrier)
    {
        int ka = lr * 4, db = g * 8;
        const u16* vb = Vhead + (size_t)ka * 32 + db;
        s16x8 r0 = *(const s16x8*)(vb);
        s16x8 r1 = *(const s16x8*)(vb + 32);
        s16x8 r2 = *(const s16x8*)(vb + 64);
        s16x8 r3 = *(const s16x8*)(vb + 96);
#pragma unroll
        for (int dd = 0; dd < 8; dd++) {
            u16x4 pk = { (u16)r0[dd], (u16)r1[dd], (u16)r2[dd], (u16)r3[dd] };
            *(u16x4*)&Vt[w][db + dd][ka] = pk;
        }
    }
    s16x8 qfr[4];
#pragma unroll
    for (int qi = 0; qi < 4; qi++) {
        int q = qi * 16 + lr;
        qfr[qi] = rot8(Qhead + q * 32 + g * 8, ct + q * 32 + g * 8, st + q * 32 + g * 8);
    }
    // per-wave LDS only -> no __syncthreads needed

    f32x4 sT[4][4] = {};
#pragma unroll
    for (int ki = 0; ki < 4; ki++) {
        s16x8 kf8 = *(const s16x8*)&K_l[w][ki * 16 + lr][g * 8];
#pragma unroll
        for (int qi = 0; qi < 4; qi++) sT[ki][qi] = MFMA(kf8, qfr[qi], sT[ki][qi]);
    }
    const float sc2 = 0.17677669529663687f * 1.4426950408889634f;
    float rsum[4];
#pragma unroll
    for (int qi = 0; qi < 4; qi++) {
        float m = -1e30f;
#pragma unroll
        for (int ki = 0; ki < 4; ki++)
#pragma unroll
            for (int r = 0; r < 4; r++) m = fmaxf(m, sT[ki][qi][r]);
        m = fmaxf(m, __shfl_xor(m, 16));
        m = fmaxf(m, __shfl_xor(m, 32));
        float msc = m * sc2;
        float ssum = 0.f;
#pragma unroll
        for (int ki = 0; ki < 4; ki++)
#pragma unroll
            for (int r = 0; r < 4; r++) {
                float p = fexp2(sT[ki][qi][r] * sc2 - msc);
                sT[ki][qi][r] = p; ssum += p;
            }
        ssum += __shfl_xor(ssum, 16);
        ssum += __shfl_xor(ssum, 32);
        rsum[qi] = 1.0f / ssum;
    }

    f32x4 o_[2][4] = {};
#pragma unroll
    for (int ks = 0; ks < 2; ks++) {
        s16x8 vf0 = *(const s16x8*)&Vt[w][lr][ks * 32 + g * 8];
        s16x8 vf1 = *(const s16x8*)&Vt[w][16 + lr][ks * 32 + g * 8];
#pragma unroll
        for (int qi = 0; qi < 4; qi++) {
            u32x2 w0 = { cvtpk(sT[2 * ks][qi][0], sT[2 * ks][qi][1]),
                         cvtpk(sT[2 * ks][qi][2], sT[2 * ks][qi][3]) };
            u32x2 w1 = { cvtpk(sT[2 * ks + 1][qi][0], sT[2 * ks + 1][qi][1]),
                         cvtpk(sT[2 * ks + 1][qi][2], sT[2 * ks + 1][qi][3]) };
            *(u32x2*)&Pst[w][qi & 1][lr][g * 4] = w0;
            *(u32x2*)&Pst[w][qi & 1][lr][16 + g * 4] = w1;
            s16x8 pf = *(const s16x8*)&Pst[w][qi & 1][lr][g * 8];
            o_[0][qi] = MFMA(vf0, pf, o_[0][qi]);
            o_[1][qi] = MFMA(vf1, pf, o_[1][qi]);
        }
    }
#pragma unroll
    for (int qi = 0; qi < 4; qi++) {
        int q = qi * 16 + lr;
        float rs = rsum[qi];
        u16* dst = y2 + ((size_t)((b * 256 + t) * 64 + q)) * 256 + h * 32;
#pragma unroll
        for (int di = 0; di < 2; di++) {
            u32x2 ob = { cvtpk(o_[di][qi][0] * rs, o_[di][qi][1] * rs),
                         cvtpk(o_[di][qi][2] * rs, o_[di][qi][3] * rs) };
            *(u32x2*)&dst[di * 16 + g * 4] = ob;
        }
    }
}

// ---------------- launch ----------------
extern "C" void kernel_launch(void* const* d_in, const int* in_sizes, int n_in,
                              void* d_out, int out_size, void* d_ws, size_t ws_size,
                              hipStream_t stream) {
    const float* x  = (const float*)d_in[0];
    const float* Wa = (const float*)d_in[1];
    const float* Wp = (const float*)d_in[2];
    const float* rt = (const float*)d_in[3];
    const float* rf = (const float*)d_in[4];
    float* out = (float*)d_out;

    u16* planes = (u16*)d_ws;           // 5 planes: q_t,q_f,k_t,k_f,v
    u16* qt  = planes;                  // idxT
    u16* qfp = planes + PL;             // idxF
    u16* ktp = planes + 2 * PL;         // idxT
    u16* kfp = planes + 3 * PL;         // idxF
    u16* vp  = planes + 4 * PL;         // idxT
    u16* y1  = planes + 5 * PL;         // idxF (time-attn out)
    u16* xb  = y1;                      // bf16 x aliases y1 slot (dead before attn_time)
    u16* y2  = ktp;                     // token-major, aliases dead k_t
    float* ct_t = (float*)(planes + 6 * PL);
    float* st_t = ct_t + 8192;
    float* ct_f = st_t + 8192;
    float* st_f = ct_f + 2048;
    u16* wt_a = (u16*)(st_f + 2048);
    u16* wt_p = wt_a + 327680;

    prep_all_k<<<8586, 256, 0, stream>>>(x, xb, Wa, Wp, rt, rf, wt_a, wt_p,
                                         ct_t, st_t, ct_f, st_f);
    gemm_k<10, true><<<5120, 256, 0, stream>>>(xb, wt_a, planes, nullptr);
    attn_time_k<<<2048, 256, 0, stream>>>(qt, ktp, vp, y1, ct_t, st_t);
    attn_freq_k<<<2048, 256, 0, stream>>>(qfp, kfp, y1, y2, ct_f, st_f);
    gemm_k<2, false><<<1024, 256, 0, stream>>>(y2, wt_p, nullptr, out);
}